// Round 4
// baseline (295.708 us; speedup 1.0000x reference)
//
#include <hip/hip_runtime.h>
#include <hip/hip_bf16.h>

#define N_NODES 50000
#define N_EDGES 1600000
#define NBUCK 98              // ceil(50000/512) buckets of 512 nodes
#define EPB 4096              // edges per binning block
#define NB_A ((N_EDGES + EPB - 1) / EPB)   // 391

typedef short bf16x8 __attribute__((ext_vector_type(8)));
typedef float f32x4  __attribute__((ext_vector_type(4)));
typedef float f32x2  __attribute__((ext_vector_type(2)));

__device__ __forceinline__ float bf16_raw_to_f32(unsigned short u) {
    return __uint_as_float(((unsigned)u) << 16);
}
__device__ __forceinline__ unsigned short f32_to_bf16_raw(float v) {
    unsigned u = __float_as_uint(v);
    return (unsigned short)((u + 0x7fffu + ((u >> 16) & 1u)) >> 16);
}
__device__ __forceinline__ float load_elem(const void* p, size_t i, int f) {
    if (f) return ((const float*)p)[i];
    return bf16_raw_to_f32(((const unsigned short*)p)[i]);
}
// unpack 8 bf16 into 4 float2 pairs (pair k = dims {2k, 2k+1})
__device__ __forceinline__ void unpack8v(uint4 u, f32x2* f) {
    f[0] = (f32x2){__uint_as_float(u.x << 16), __uint_as_float(u.x & 0xffff0000u)};
    f[1] = (f32x2){__uint_as_float(u.y << 16), __uint_as_float(u.y & 0xffff0000u)};
    f[2] = (f32x2){__uint_as_float(u.z << 16), __uint_as_float(u.z & 0xffff0000u)};
    f[3] = (f32x2){__uint_as_float(u.w << 16), __uint_as_float(u.w & 0xffff0000u)};
}

// ---- dtype probe (verified R4): flag=1 -> fp32 storage. Also zeroes bcnt.
__global__ void detect_dtype_kernel(const unsigned short* __restrict__ w1raw,
                                    int* __restrict__ flag, int* __restrict__ bcnt) {
    __shared__ float red[256];
    if (threadIdx.x < NBUCK) bcnt[threadIdx.x] = 0;
    float mx = 0.f;
    for (int i = threadIdx.x * 2; i < 16384; i += 512) {
        float v = fabsf(bf16_raw_to_f32(w1raw[i]));
        if (!isnan(v)) mx = fmaxf(mx, v);
    }
    red[threadIdx.x] = mx;
    __syncthreads();
    for (int s = 128; s > 0; s >>= 1) {
        if (threadIdx.x < s) red[threadIdx.x] = fmaxf(red[threadIdx.x], red[threadIdx.x + s]);
        __syncthreads();
    }
    if (threadIdx.x == 0) flag[0] = (red[0] > 1e4f) ? 1 : 0;
}

// ---- prep: W1T[n][k] (128x136 bf16), W2T[n][k] (64x136 bf16) ----
#define WPAD 136
__global__ void prep_kernel(const void* __restrict__ W1, const void* __restrict__ W2,
                            unsigned short* __restrict__ W1T,
                            unsigned short* __restrict__ W2T,
                            const int* __restrict__ flag) {
    const int f = *flag;
    int bid = blockIdx.x, tid = threadIdx.x;
    if (bid < 8) {
        int n = bid * 16 + (tid & 15);
        int kb = (tid >> 4) * 8;
        for (int j = 0; j < 8; ++j)
            W1T[n * WPAD + kb + j] = f32_to_bf16_raw(load_elem(W1, (size_t)(kb + j) * 128 + n, f));
    } else {
        int n = (bid - 8) * 16 + (tid & 15);
        int kb = (tid >> 4) * 8;
        for (int j = 0; j < 8; ++j)
            W2T[n * WPAD + kb + j] = f32_to_bf16_raw(load_elem(W2, (size_t)(kb + j) * 64 + n, f));
    }
}

// ============ binned CSR build (R12-proven) ============
__global__ void bucket_count_kernel(const int* __restrict__ dst,
                                    int* __restrict__ bcnt, int E) {
    __shared__ int hist[NBUCK];
    int t = threadIdx.x;
    if (t < NBUCK) hist[t] = 0;
    __syncthreads();
    int e0 = blockIdx.x * EPB;
    for (int k = 0; k < 16; ++k) {
        int e = e0 + k * 256 + t;
        if (e < E) atomicAdd(&hist[dst[e] >> 9], 1);
    }
    __syncthreads();
    if (t < NBUCK && hist[t]) atomicAdd(&bcnt[t], hist[t]);
}

__global__ void bucket_scan_kernel(const int* __restrict__ bcnt,
                                   int* __restrict__ bbase, int* __restrict__ bcur) {
    __shared__ int tmp[128];
    int t = threadIdx.x;
    int v = (t < NBUCK) ? bcnt[t] : 0;
    tmp[t] = v;
    __syncthreads();
    for (int off = 1; off < 128; off <<= 1) {
        int x = (t >= off) ? tmp[t - off] : 0;
        __syncthreads();
        tmp[t] += x;
        __syncthreads();
    }
    if (t < NBUCK) { int ex = tmp[t] - v; bbase[t] = ex; bcur[t] = ex; }
    if (t == NBUCK - 1) bbase[NBUCK] = tmp[t];
}

__global__ void binA_kernel(const int* __restrict__ src, const int* __restrict__ dst,
                            int* __restrict__ bcur, unsigned* __restrict__ inter, int E) {
    __shared__ int hist[NBUCK], gbase[NBUCK], cur[NBUCK];
    int t = threadIdx.x;
    if (t < NBUCK) hist[t] = 0;
    __syncthreads();
    int e0 = blockIdx.x * EPB;
    for (int k = 0; k < 16; ++k) {
        int e = e0 + k * 256 + t;
        if (e < E) atomicAdd(&hist[dst[e] >> 9], 1);
    }
    __syncthreads();
    if (t < NBUCK) {
        int hv = hist[t];
        gbase[t] = hv ? atomicAdd(&bcur[t], hv) : 0;
        cur[t] = 0;
    }
    __syncthreads();
    for (int k = 0; k < 16; ++k) {
        int e = e0 + k * 256 + t;
        if (e < E) {
            int d = dst[e];
            int b = d >> 9;
            int off = atomicAdd(&cur[b], 1);
            inter[gbase[b] + off] = (unsigned)src[e] | ((unsigned)(d & 511) << 16);
        }
    }
}

__global__ void binB_kernel(const unsigned* __restrict__ inter,
                            const int* __restrict__ bbase,
                            int* __restrict__ csr_src, int* __restrict__ start,
                            int N, int E) {
    int b = blockIdx.x;
    int node0 = b << 9;
    int lo = bbase[b], hi = bbase[b + 1];
    __shared__ int hist[512];
    __shared__ int t2[256];
    int t = threadIdx.x;
    hist[t] = 0; hist[t + 256] = 0;
    __syncthreads();
    for (int e = lo + t; e < hi; e += 256) atomicAdd(&hist[inter[e] >> 16], 1);
    __syncthreads();
    int s0 = hist[2 * t], s1 = hist[2 * t + 1];
    t2[t] = s0 + s1;
    __syncthreads();
    for (int off = 1; off < 256; off <<= 1) {
        int x = (t >= off) ? t2[t - off] : 0;
        __syncthreads();
        t2[t] += x;
        __syncthreads();
    }
    int base = (t == 0) ? 0 : t2[t - 1];
    hist[2 * t] = base;
    hist[2 * t + 1] = base + s0;
    __syncthreads();
    int nodeCnt = min(512, N - node0);
    for (int i = t; i < nodeCnt; i += 256) start[node0 + i] = lo + hist[i];
    if (b == NBUCK - 1 && t == 0) start[N] = E;
    __syncthreads();
    for (int e = lo + t; e < hi; e += 256) {
        unsigned u = inter[e];
        int slot = lo + atomicAdd(&hist[u >> 16], 1);
        csr_src[slot] = (int)(u & 0xffffu);
    }
}

// ---- MFMA GEMM1 (R9-proven) ----
__global__ void gemm1_mfma_kernel(const void* __restrict__ h,
                                  const unsigned short* __restrict__ W1T,
                                  unsigned short* __restrict__ feat1, int N,
                                  const int* __restrict__ flag) {
    const int f = *flag;
    int lane = threadIdx.x & 63;
    int rbase = blockIdx.x * 64 + (threadIdx.x >> 6) * 16;
    int arow = rbase + (lane & 15);
    int arowc = min(arow, N - 1);
    int kb0 = (lane >> 4) * 8;

    f32x4 acc[8];
#pragma unroll
    for (int t = 0; t < 8; ++t) acc[t] = (f32x4){0.f, 0.f, 0.f, 0.f};

#pragma unroll
    for (int ks = 0; ks < 4; ++ks) {
        int kb = ks * 32 + kb0;
        bf16x8 afrag;
        if (f == 0) {
            afrag = *(const bf16x8*)((const unsigned short*)h + (size_t)arowc * 128 + kb);
        } else {
            const float* hp = (const float*)h + (size_t)arowc * 128 + kb;
#pragma unroll
            for (int j = 0; j < 8; ++j) afrag[j] = (short)f32_to_bf16_raw(hp[j]);
        }
#pragma unroll
        for (int t = 0; t < 8; ++t) {
            int n = t * 16 + (lane & 15);
            bf16x8 bfrag = *(const bf16x8*)(W1T + n * WPAD + kb);
            acc[t] = __builtin_amdgcn_mfma_f32_16x16x32_bf16(afrag, bfrag, acc[t], 0, 0, 0);
        }
    }
    int orow0 = rbase + (lane >> 4) * 4;
    int col = lane & 15;
#pragma unroll
    for (int t = 0; t < 8; ++t)
#pragma unroll
        for (int r = 0; r < 4; ++r) {
            int row = orow0 + r;
            if (row < N)
                feat1[(size_t)row * 128 + t * 16 + col] = f32_to_bf16_raw(acc[t][r]);
        }
}

// ---- MFMA GEMM2 (R9-proven) ----
__global__ void gemm2_mfma_kernel(const unsigned short* __restrict__ agg1e,
                                  const unsigned short* __restrict__ W2T,
                                  unsigned short* __restrict__ feat2, int N) {
    int lane = threadIdx.x & 63;
    int rbase = blockIdx.x * 64 + (threadIdx.x >> 6) * 16;
    int arow = rbase + (lane & 15);
    int arowc = min(arow, N - 1);
    int kb0 = (lane >> 4) * 8;

    f32x4 acc[4];
#pragma unroll
    for (int t = 0; t < 4; ++t) acc[t] = (f32x4){0.f, 0.f, 0.f, 0.f};

#pragma unroll
    for (int ks = 0; ks < 4; ++ks) {
        int kb = ks * 32 + kb0;
        bf16x8 afrag = *(const bf16x8*)(agg1e + (size_t)arowc * 128 + kb);
#pragma unroll
        for (int t = 0; t < 4; ++t) {
            int n = t * 16 + (lane & 15);
            bf16x8 bfrag = *(const bf16x8*)(W2T + n * WPAD + kb);
            acc[t] = __builtin_amdgcn_mfma_f32_16x16x32_bf16(afrag, bfrag, acc[t], 0, 0, 0);
        }
    }
    int orow0 = rbase + (lane >> 4) * 4;
    int col = lane & 15;
#pragma unroll
    for (int t = 0; t < 4; ++t)
#pragma unroll
        for (int r = 0; r < 4; ++r) {
            int row = orow0 + r;
            if (row < N)
                feat2[(size_t)row * 64 + t * 16 + col] = f32_to_bf16_raw(acc[t][r]);
        }
}

// ======= layer 1 fused GAT (R17) =======
// Wave = 1 dst (50000 waves: restores R14's latency hiding / occupancy).
// 8 groups x 8 lanes; lane owns one full head (16 dims = 2 uint4): head
// dot is lane-local -> zero per-edge shfl (the R16 instruction win).
// Groups STRIDE the dst's edge list (group g takes base+g, base+8+g):
// serial loop = deg/16 iters, 4 outstanding 16B gathers/lane, csr_src
// reads = one contiguous 64B line per wave.
// Per-node cost: 3-round x 17-reg shfl merge (~1.6 slots/edge).
__global__ void gat1_kernel(const unsigned short* __restrict__ feat1,
                            const int* __restrict__ csr_src,
                            const int* __restrict__ start,
                            unsigned short* __restrict__ agg1e, int N) {
    int dstn = blockIdx.x * 4 + (threadIdx.x >> 6);
    if (dstn >= N) return;
    int lane = threadIdx.x & 63;
    int g = lane >> 3, gl = lane & 7;          // g=edge-slot, gl=head

    const char* fb = (const char*)feat1;       // row = 256 B
    unsigned loff = (unsigned)gl << 5;         // 32 B per head
    unsigned drow = ((unsigned)dstn << 8) + loff;
    f32x2 fd2[8];
    unpack8v(*(const uint4*)(fb + drow), fd2);
    unpack8v(*(const uint4*)(fb + drow + 16), fd2 + 4);

    float l = 0.f;
    f32x2 acc2[8];
#pragma unroll
    for (int k = 0; k < 8; ++k) acc2[k] = (f32x2){0.f, 0.f};

    int e0 = start[dstn], e1 = start[dstn + 1];
    int base = e0;
    for (; base + 16 <= e1; base += 16) {
        int s0 = csr_src[base + g];
        int s1 = csr_src[base + 8 + g];
        const char* r0 = fb + ((unsigned)s0 << 8) + loff;
        const char* r1 = fb + ((unsigned)s1 << 8) + loff;
        uint4 a0 = *(const uint4*)r0, a1 = *(const uint4*)(r0 + 16);
        uint4 b0 = *(const uint4*)r1, b1 = *(const uint4*)(r1 + 16);
        f32x2 f0[8], f1[8];
        unpack8v(a0, f0); unpack8v(a1, f0 + 4);
        unpack8v(b0, f1); unpack8v(b1, f1 + 4);
        f32x2 p0 = fd2[0] * f0[0];
        f32x2 p1 = fd2[0] * f1[0];
#pragma unroll
        for (int k = 1; k < 8; ++k) { p0 += fd2[k] * f0[k]; p1 += fd2[k] * f1[k]; }
        float w0 = __expf((p0.x + p0.y) * 0.25f);
        float w1 = __expf((p1.x + p1.y) * 0.25f);
        f32x2 W0 = (f32x2){w0, w0}, W1 = (f32x2){w1, w1};
#pragma unroll
        for (int k = 0; k < 8; ++k) {
            acc2[k] += W0 * f0[k];
            acc2[k] += W1 * f1[k];
        }
        l += w0 + w1;
    }
    for (; base < e1; base += 8) {             // masked tail, 8 edges/step
        int ed = base + g;
        bool act = ed < e1;
        int s = act ? csr_src[ed] : 0;
        const char* r0 = fb + ((unsigned)s << 8) + loff;
        uint4 a0 = *(const uint4*)r0, a1 = *(const uint4*)(r0 + 16);
        f32x2 fv[8];
        unpack8v(a0, fv); unpack8v(a1, fv + 4);
        f32x2 p = fd2[0] * fv[0];
#pragma unroll
        for (int k = 1; k < 8; ++k) p += fd2[k] * fv[k];
        float w = act ? __expf((p.x + p.y) * 0.25f) : 0.f;
        f32x2 W = (f32x2){w, w};
#pragma unroll
        for (int k = 0; k < 8; ++k) acc2[k] += W * fv[k];
        l += w;
    }
    // merge the 8 edge-slot groups (pure sums)
#pragma unroll
    for (int off = 8; off <= 32; off <<= 1) {
        l += __shfl_xor(l, off);
#pragma unroll
        for (int k = 0; k < 8; ++k) {
            acc2[k].x += __shfl_xor(acc2[k].x, off);
            acc2[k].y += __shfl_xor(acc2[k].y, off);
        }
    }
    if (g == 0) {
        float rcp = 1.f / fmaxf(l, 1e-9f);
        unsigned pk[8];
#pragma unroll
        for (int k = 0; k < 8; ++k) {
            float x0 = acc2[k].x * rcp, x1 = acc2[k].y * rcp;
            x0 = (x0 > 0.f) ? x0 : expm1f(x0);     // ELU fused
            x1 = (x1 > 0.f) ? x1 : expm1f(x1);
            pk[k] = (unsigned)f32_to_bf16_raw(x0) | ((unsigned)f32_to_bf16_raw(x1) << 16);
        }
        *(uint4*)((char*)agg1e + drow)      = (uint4){pk[0], pk[1], pk[2], pk[3]};
        *(uint4*)((char*)agg1e + drow + 16) = (uint4){pk[4], pk[5], pk[6], pk[7]};
    }
}

// ======= layer 2 fused GAT (R14-proven form) =======
// Wave = 1 dst; 8 groups x 8 lanes; lane = 8 dims (1 uint4).
// 64-dim dot needs 3 intra-group shfls/edge; groups stride edges.
__global__ void gat2_kernel(const unsigned short* __restrict__ feat2,
                            const int* __restrict__ csr_src,
                            const int* __restrict__ start,
                            void* __restrict__ out, int N,
                            const int* __restrict__ flag) {
    int wave = blockIdx.x * 4 + (threadIdx.x >> 6);
    if (wave >= N) return;
    int lane = threadIdx.x & 63;
    int grp = lane >> 3, gl = lane & 7;
    const int f = *flag;
    const char* fb = (const char*)feat2;       // row = 128 B
    unsigned loff = (unsigned)gl << 4;
    f32x2 fd2[4];
    unpack8v(*(const uint4*)(fb + (((unsigned)wave << 7) + loff)), fd2);

    float l = 0.f;
    f32x2 acc2[4];
#pragma unroll
    for (int k = 0; k < 4; ++k) acc2[k] = (f32x2){0.f, 0.f};

    int e0 = start[wave], e1 = start[wave + 1];
    int base = e0;
    for (; base + 16 <= e1; base += 16) {
        int s0 = csr_src[base + grp];
        int s1 = csr_src[base + 8 + grp];
        uint4 u0 = *(const uint4*)(fb + (((unsigned)s0 << 7) + loff));
        uint4 u1 = *(const uint4*)(fb + (((unsigned)s1 << 7) + loff));
        f32x2 f0[4], f1[4];
        unpack8v(u0, f0); unpack8v(u1, f1);
        f32x2 p0 = fd2[0] * f0[0];
        f32x2 p1 = fd2[0] * f1[0];
#pragma unroll
        for (int k = 1; k < 4; ++k) { p0 += fd2[k] * f0[k]; p1 += fd2[k] * f1[k]; }
        float q0 = p0.x + p0.y;
        float q1 = p1.x + p1.y;
        q0 += __shfl_xor(q0, 1); q1 += __shfl_xor(q1, 1);
        q0 += __shfl_xor(q0, 2); q1 += __shfl_xor(q1, 2);
        q0 += __shfl_xor(q0, 4); q1 += __shfl_xor(q1, 4);
        float w0 = __expf(q0 * 0.125f);
        float w1 = __expf(q1 * 0.125f);
        f32x2 W0 = (f32x2){w0, w0}, W1 = (f32x2){w1, w1};
#pragma unroll
        for (int k = 0; k < 4; ++k) {
            acc2[k] += W0 * f0[k];
            acc2[k] += W1 * f1[k];
        }
        l += w0 + w1;
    }
    for (; base < e1; base += 8) {
        int ed = base + grp;
        bool act = ed < e1;
        int s = act ? csr_src[ed] : 0;
        uint4 u = *(const uint4*)(fb + (((unsigned)s << 7) + loff));
        f32x2 fv[4];
        unpack8v(u, fv);
        f32x2 p = fd2[0] * fv[0];
#pragma unroll
        for (int k = 1; k < 4; ++k) p += fd2[k] * fv[k];
        float q = p.x + p.y;
        q += __shfl_xor(q, 1);
        q += __shfl_xor(q, 2);
        q += __shfl_xor(q, 4);
        float w = act ? __expf(q * 0.125f) : 0.f;
        f32x2 W = (f32x2){w, w};
#pragma unroll
        for (int k = 0; k < 4; ++k) acc2[k] += W * fv[k];
        l += w;
    }
#pragma unroll
    for (int off = 8; off <= 32; off <<= 1) {
        l += __shfl_xor(l, off);
#pragma unroll
        for (int k = 0; k < 4; ++k) {
            acc2[k].x += __shfl_xor(acc2[k].x, off);
            acc2[k].y += __shfl_xor(acc2[k].y, off);
        }
    }
    if (grp == 0) {
        float rcp = 1.f / fmaxf(l, 1e-9f);
        float v[8];
#pragma unroll
        for (int k = 0; k < 4; ++k) {
            v[2 * k]     = acc2[k].x * rcp;
            v[2 * k + 1] = acc2[k].y * rcp;
        }
        if (f) {
            float* op = (float*)out + ((size_t)wave << 6) + (gl << 3);
            *(float4*)(op)     = (float4){v[0], v[1], v[2], v[3]};
            *(float4*)(op + 4) = (float4){v[4], v[5], v[6], v[7]};
        } else {
            uint4 pk;
            pk.x = (unsigned)f32_to_bf16_raw(v[0]) | ((unsigned)f32_to_bf16_raw(v[1]) << 16);
            pk.y = (unsigned)f32_to_bf16_raw(v[2]) | ((unsigned)f32_to_bf16_raw(v[3]) << 16);
            pk.z = (unsigned)f32_to_bf16_raw(v[4]) | ((unsigned)f32_to_bf16_raw(v[5]) << 16);
            pk.w = (unsigned)f32_to_bf16_raw(v[6]) | ((unsigned)f32_to_bf16_raw(v[7]) << 16);
            *(uint4*)((unsigned short*)out + ((size_t)wave << 6) + (gl << 3)) = pk;
        }
    }
}

extern "C" void kernel_launch(void* const* d_in, const int* in_sizes, int n_in,
                              void* d_out, int out_size, void* d_ws, size_t ws_size,
                              hipStream_t stream) {
    const void* h  = d_in[0];
    const void* W1 = d_in[1];
    const void* W2 = d_in[2];
    const int* src = (const int*)d_in[3];
    const int* dst = (const int*)d_in[4];

    float* ws = (float*)d_ws;
    // Layout (4-byte words), peak ~45.5 MB.
    unsigned short* feat1 = (unsigned short*)ws;
    unsigned short* agg1e = (unsigned short*)(ws + 3200000);
    unsigned short* feat2 = (unsigned short*)ws;      // after feat1 dead
    unsigned* inter       = (unsigned*)(ws + 6400000);
    int*   csr_src        = (int*)(ws + 9600000);
    int*   start          = (int*)(ws + 11200000);
    int*   flag           = (int*)(ws + 11330000);
    int*   bcnt           = (int*)(ws + 11331000);
    int*   bbase          = (int*)(ws + 11332000);
    int*   bcur           = (int*)(ws + 11333000);
    unsigned short* W1T   = (unsigned short*)(ws + 11340000);
    unsigned short* W2T   = (unsigned short*)(ws + 11350000);

    detect_dtype_kernel<<<1, 256, 0, stream>>>((const unsigned short*)W1, flag, bcnt);
    prep_kernel<<<12, 256, 0, stream>>>(W1, W2, W1T, W2T, flag);

    // ---- binned CSR build (by dst), storing src ids ----
    bucket_count_kernel<<<NB_A, 256, 0, stream>>>(dst, bcnt, N_EDGES);
    bucket_scan_kernel<<<1, 128, 0, stream>>>(bcnt, bbase, bcur);
    binA_kernel<<<NB_A, 256, 0, stream>>>(src, dst, bcur, inter, N_EDGES);
    binB_kernel<<<NBUCK, 256, 0, stream>>>(inter, bbase, csr_src, start, N_NODES, N_EDGES);

    gemm1_mfma_kernel<<<(N_NODES + 63) / 64, 256, 0, stream>>>(h, W1T, feat1, N_NODES, flag);
    gat1_kernel<<<(N_NODES + 3) / 4, 256, 0, stream>>>(feat1, csr_src, start, agg1e, N_NODES);
    gemm2_mfma_kernel<<<(N_NODES + 63) / 64, 256, 0, stream>>>(agg1e, W2T, feat2, N_NODES);
    gat2_kernel<<<(N_NODES + 3) / 4, 256, 0, stream>>>(feat2, csr_src, start, d_out, N_NODES, flag);
}

// Round 5
// 285.075 us; speedup vs baseline: 1.0373x; 1.0373x over previous
//
#include <hip/hip_runtime.h>
#include <hip/hip_bf16.h>

#define N_NODES 50000
#define N_EDGES 1600000
#define NBUCK 98              // ceil(50000/512) buckets of 512 nodes
#define EPB 4096              // edges per binning block
#define NB_A ((N_EDGES + EPB - 1) / EPB)   // 391

typedef short bf16x8 __attribute__((ext_vector_type(8)));
typedef float f32x4  __attribute__((ext_vector_type(4)));
typedef float f32x2  __attribute__((ext_vector_type(2)));

#if __has_builtin(__builtin_amdgcn_exp2f)
#define EXP2(x) __builtin_amdgcn_exp2f(x)
#else
#define EXP2(x) exp2f(x)
#endif
#define LOG2E 1.44269504088896340736f

__device__ __forceinline__ float bf16_raw_to_f32(unsigned short u) {
    return __uint_as_float(((unsigned)u) << 16);
}
__device__ __forceinline__ unsigned short f32_to_bf16_raw(float v) {
    unsigned u = __float_as_uint(v);
    return (unsigned short)((u + 0x7fffu + ((u >> 16) & 1u)) >> 16);
}
__device__ __forceinline__ float load_elem(const void* p, size_t i, int f) {
    if (f) return ((const float*)p)[i];
    return bf16_raw_to_f32(((const unsigned short*)p)[i]);
}
// unpack 8 bf16 into 4 float2 pairs (pair k = dims {2k, 2k+1})
__device__ __forceinline__ void unpack8v(uint4 u, f32x2* f) {
    f[0] = (f32x2){__uint_as_float(u.x << 16), __uint_as_float(u.x & 0xffff0000u)};
    f[1] = (f32x2){__uint_as_float(u.y << 16), __uint_as_float(u.y & 0xffff0000u)};
    f[2] = (f32x2){__uint_as_float(u.z << 16), __uint_as_float(u.z & 0xffff0000u)};
    f[3] = (f32x2){__uint_as_float(u.w << 16), __uint_as_float(u.w & 0xffff0000u)};
}

// ---- dtype probe (verified R4): flag=1 -> fp32 storage. Also zeroes bcnt.
__global__ void detect_dtype_kernel(const unsigned short* __restrict__ w1raw,
                                    int* __restrict__ flag, int* __restrict__ bcnt) {
    __shared__ float red[256];
    if (threadIdx.x < NBUCK) bcnt[threadIdx.x] = 0;
    float mx = 0.f;
    for (int i = threadIdx.x * 2; i < 16384; i += 512) {
        float v = fabsf(bf16_raw_to_f32(w1raw[i]));
        if (!isnan(v)) mx = fmaxf(mx, v);
    }
    red[threadIdx.x] = mx;
    __syncthreads();
    for (int s = 128; s > 0; s >>= 1) {
        if (threadIdx.x < s) red[threadIdx.x] = fmaxf(red[threadIdx.x], red[threadIdx.x + s]);
        __syncthreads();
    }
    if (threadIdx.x == 0) flag[0] = (red[0] > 1e4f) ? 1 : 0;
}

// ---- prep: W1T[n][k] (128x136 bf16), W2T[n][k] (64x136 bf16) ----
#define WPAD 136
__global__ void prep_kernel(const void* __restrict__ W1, const void* __restrict__ W2,
                            unsigned short* __restrict__ W1T,
                            unsigned short* __restrict__ W2T,
                            const int* __restrict__ flag) {
    const int f = *flag;
    int bid = blockIdx.x, tid = threadIdx.x;
    if (bid < 8) {
        int n = bid * 16 + (tid & 15);
        int kb = (tid >> 4) * 8;
        for (int j = 0; j < 8; ++j)
            W1T[n * WPAD + kb + j] = f32_to_bf16_raw(load_elem(W1, (size_t)(kb + j) * 128 + n, f));
    } else {
        int n = (bid - 8) * 16 + (tid & 15);
        int kb = (tid >> 4) * 8;
        for (int j = 0; j < 8; ++j)
            W2T[n * WPAD + kb + j] = f32_to_bf16_raw(load_elem(W2, (size_t)(kb + j) * 64 + n, f));
    }
}

// ============ binned CSR build (R12-proven) ============
__global__ void bucket_count_kernel(const int* __restrict__ dst,
                                    int* __restrict__ bcnt, int E) {
    __shared__ int hist[NBUCK];
    int t = threadIdx.x;
    if (t < NBUCK) hist[t] = 0;
    __syncthreads();
    int e0 = blockIdx.x * EPB;
    for (int k = 0; k < 16; ++k) {
        int e = e0 + k * 256 + t;
        if (e < E) atomicAdd(&hist[dst[e] >> 9], 1);
    }
    __syncthreads();
    if (t < NBUCK && hist[t]) atomicAdd(&bcnt[t], hist[t]);
}

__global__ void bucket_scan_kernel(const int* __restrict__ bcnt,
                                   int* __restrict__ bbase, int* __restrict__ bcur) {
    __shared__ int tmp[128];
    int t = threadIdx.x;
    int v = (t < NBUCK) ? bcnt[t] : 0;
    tmp[t] = v;
    __syncthreads();
    for (int off = 1; off < 128; off <<= 1) {
        int x = (t >= off) ? tmp[t - off] : 0;
        __syncthreads();
        tmp[t] += x;
        __syncthreads();
    }
    if (t < NBUCK) { int ex = tmp[t] - v; bbase[t] = ex; bcur[t] = ex; }
    if (t == NBUCK - 1) bbase[NBUCK] = tmp[t];
}

__global__ void binA_kernel(const int* __restrict__ src, const int* __restrict__ dst,
                            int* __restrict__ bcur, unsigned* __restrict__ inter, int E) {
    __shared__ int hist[NBUCK], gbase[NBUCK], cur[NBUCK];
    int t = threadIdx.x;
    if (t < NBUCK) hist[t] = 0;
    __syncthreads();
    int e0 = blockIdx.x * EPB;
    for (int k = 0; k < 16; ++k) {
        int e = e0 + k * 256 + t;
        if (e < E) atomicAdd(&hist[dst[e] >> 9], 1);
    }
    __syncthreads();
    if (t < NBUCK) {
        int hv = hist[t];
        gbase[t] = hv ? atomicAdd(&bcur[t], hv) : 0;
        cur[t] = 0;
    }
    __syncthreads();
    for (int k = 0; k < 16; ++k) {
        int e = e0 + k * 256 + t;
        if (e < E) {
            int d = dst[e];
            int b = d >> 9;
            int off = atomicAdd(&cur[b], 1);
            inter[gbase[b] + off] = (unsigned)src[e] | ((unsigned)(d & 511) << 16);
        }
    }
}

__global__ void binB_kernel(const unsigned* __restrict__ inter,
                            const int* __restrict__ bbase,
                            int* __restrict__ csr_src, int* __restrict__ start,
                            int N, int E) {
    int b = blockIdx.x;
    int node0 = b << 9;
    int lo = bbase[b], hi = bbase[b + 1];
    __shared__ int hist[512];
    __shared__ int t2[256];
    int t = threadIdx.x;
    hist[t] = 0; hist[t + 256] = 0;
    __syncthreads();
    for (int e = lo + t; e < hi; e += 256) atomicAdd(&hist[inter[e] >> 16], 1);
    __syncthreads();
    int s0 = hist[2 * t], s1 = hist[2 * t + 1];
    t2[t] = s0 + s1;
    __syncthreads();
    for (int off = 1; off < 256; off <<= 1) {
        int x = (t >= off) ? t2[t - off] : 0;
        __syncthreads();
        t2[t] += x;
        __syncthreads();
    }
    int base = (t == 0) ? 0 : t2[t - 1];
    hist[2 * t] = base;
    hist[2 * t + 1] = base + s0;
    __syncthreads();
    int nodeCnt = min(512, N - node0);
    for (int i = t; i < nodeCnt; i += 256) start[node0 + i] = lo + hist[i];
    if (b == NBUCK - 1 && t == 0) start[N] = E;
    __syncthreads();
    for (int e = lo + t; e < hi; e += 256) {
        unsigned u = inter[e];
        int slot = lo + atomicAdd(&hist[u >> 16], 1);
        csr_src[slot] = (int)(u & 0xffffu);
    }
}

// ---- MFMA GEMM1 (R9-proven) ----
__global__ void gemm1_mfma_kernel(const void* __restrict__ h,
                                  const unsigned short* __restrict__ W1T,
                                  unsigned short* __restrict__ feat1, int N,
                                  const int* __restrict__ flag) {
    const int f = *flag;
    int lane = threadIdx.x & 63;
    int rbase = blockIdx.x * 64 + (threadIdx.x >> 6) * 16;
    int arow = rbase + (lane & 15);
    int arowc = min(arow, N - 1);
    int kb0 = (lane >> 4) * 8;

    f32x4 acc[8];
#pragma unroll
    for (int t = 0; t < 8; ++t) acc[t] = (f32x4){0.f, 0.f, 0.f, 0.f};

#pragma unroll
    for (int ks = 0; ks < 4; ++ks) {
        int kb = ks * 32 + kb0;
        bf16x8 afrag;
        if (f == 0) {
            afrag = *(const bf16x8*)((const unsigned short*)h + (size_t)arowc * 128 + kb);
        } else {
            const float* hp = (const float*)h + (size_t)arowc * 128 + kb;
#pragma unroll
            for (int j = 0; j < 8; ++j) afrag[j] = (short)f32_to_bf16_raw(hp[j]);
        }
#pragma unroll
        for (int t = 0; t < 8; ++t) {
            int n = t * 16 + (lane & 15);
            bf16x8 bfrag = *(const bf16x8*)(W1T + n * WPAD + kb);
            acc[t] = __builtin_amdgcn_mfma_f32_16x16x32_bf16(afrag, bfrag, acc[t], 0, 0, 0);
        }
    }
    int orow0 = rbase + (lane >> 4) * 4;
    int col = lane & 15;
#pragma unroll
    for (int t = 0; t < 8; ++t)
#pragma unroll
        for (int r = 0; r < 4; ++r) {
            int row = orow0 + r;
            if (row < N)
                feat1[(size_t)row * 128 + t * 16 + col] = f32_to_bf16_raw(acc[t][r]);
        }
}

// ---- MFMA GEMM2 (R9-proven) ----
__global__ void gemm2_mfma_kernel(const unsigned short* __restrict__ agg1e,
                                  const unsigned short* __restrict__ W2T,
                                  unsigned short* __restrict__ feat2, int N) {
    int lane = threadIdx.x & 63;
    int rbase = blockIdx.x * 64 + (threadIdx.x >> 6) * 16;
    int arow = rbase + (lane & 15);
    int arowc = min(arow, N - 1);
    int kb0 = (lane >> 4) * 8;

    f32x4 acc[4];
#pragma unroll
    for (int t = 0; t < 4; ++t) acc[t] = (f32x4){0.f, 0.f, 0.f, 0.f};

#pragma unroll
    for (int ks = 0; ks < 4; ++ks) {
        int kb = ks * 32 + kb0;
        bf16x8 afrag = *(const bf16x8*)(agg1e + (size_t)arowc * 128 + kb);
#pragma unroll
        for (int t = 0; t < 4; ++t) {
            int n = t * 16 + (lane & 15);
            bf16x8 bfrag = *(const bf16x8*)(W2T + n * WPAD + kb);
            acc[t] = __builtin_amdgcn_mfma_f32_16x16x32_bf16(afrag, bfrag, acc[t], 0, 0, 0);
        }
    }
    int orow0 = rbase + (lane >> 4) * 4;
    int col = lane & 15;
#pragma unroll
    for (int t = 0; t < 4; ++t)
#pragma unroll
        for (int r = 0; r < 4; ++r) {
            int row = orow0 + r;
            if (row < N)
                feat2[(size_t)row * 64 + t * 16 + col] = f32_to_bf16_raw(acc[t][r]);
        }
}

// ======= layer 1 fused GAT (R18 = R14 structure + software pipeline) =======
// Wave = 1 dst; 4 groups x 16 lanes (16-lane group loads one full 256B row
// per VMEM inst = best-coalesced of all tried layouts, measured R14/16/17).
// R18: prefetch next iteration's csr indices + feature gathers before
// processing the current one (breaks csr->addr->gather->use serial chain);
// exp folded into prescaled fd (exp2 path, zero per-edge argument muls).
#define GAT1_PROC(U0, U1)                                                     \
    {                                                                         \
        f32x2 f0[4], f1[4];                                                   \
        unpack8v(U0, f0); unpack8v(U1, f1);                                   \
        f32x2 p0 = fd2[0] * f0[0];                                            \
        f32x2 p1 = fd2[0] * f1[0];                                            \
        _Pragma("unroll")                                                     \
        for (int k = 1; k < 4; ++k) { p0 += fd2[k] * f0[k]; p1 += fd2[k] * f1[k]; } \
        float q0 = p0.x + p0.y, q1 = p1.x + p1.y;                             \
        q0 += __shfl_xor(q0, 1); q1 += __shfl_xor(q1, 1);                     \
        float w0 = EXP2(q0), w1 = EXP2(q1);                                   \
        f32x2 W0 = (f32x2){w0, w0}, W1 = (f32x2){w1, w1};                     \
        _Pragma("unroll")                                                     \
        for (int k = 0; k < 4; ++k) { acc2[k] += W0 * f0[k]; acc2[k] += W1 * f1[k]; } \
        l += w0 + w1;                                                         \
    }

__global__ void gat1_kernel(const unsigned short* __restrict__ feat1,
                            const int* __restrict__ csr_src,
                            const int* __restrict__ start,
                            unsigned short* __restrict__ agg1e, int N) {
    int wave = blockIdx.x * 4 + (threadIdx.x >> 6);
    if (wave >= N) return;
    int lane = threadIdx.x & 63;
    int grp = lane >> 4, gl = lane & 15;
    const char* fb = (const char*)feat1;       // uniform base; row = 256 B
    unsigned loff = (unsigned)gl << 4;
    f32x2 fd2[4];
    unpack8v(*(const uint4*)(fb + (((unsigned)wave << 8) + loff)), fd2);
    const float SC = 0.25f * LOG2E;            // fold score scale + log2e
    const f32x2 SC2 = (f32x2){SC, SC};
#pragma unroll
    for (int k = 0; k < 4; ++k) fd2[k] *= SC2;

    float l = 0.f;
    f32x2 acc2[4];
#pragma unroll
    for (int k = 0; k < 4; ++k) acc2[k] = (f32x2){0.f, 0.f};

    int e0 = start[wave], e1 = start[wave + 1];
    int nfull = (e1 - e0) >> 3;                // full 8-edge iterations
    int base = e0;
    uint4 u0, u1;
    if (nfull > 0) {
        int s0 = csr_src[base + grp];
        int s1 = csr_src[base + 4 + grp];
        u0 = *(const uint4*)(fb + (((unsigned)s0 << 8) + loff));
        u1 = *(const uint4*)(fb + (((unsigned)s1 << 8) + loff));
    }
    for (int it = 0; it < nfull - 1; ++it) {   // pipelined: prefetch iter+1
        int nb = base + 8;
        int s0 = csr_src[nb + grp];
        int s1 = csr_src[nb + 4 + grp];
        uint4 n0 = *(const uint4*)(fb + (((unsigned)s0 << 8) + loff));
        uint4 n1 = *(const uint4*)(fb + (((unsigned)s1 << 8) + loff));
        GAT1_PROC(u0, u1);
        u0 = n0; u1 = n1; base = nb;
    }
    if (nfull > 0) { GAT1_PROC(u0, u1); base += 8; }
    for (; base < e1; base += 4) {             // masked tail, 4 edges/step
        int ed = base + grp;
        bool act = ed < e1;
        int s = act ? csr_src[ed] : 0;
        uint4 u = *(const uint4*)(fb + (((unsigned)s << 8) + loff));
        f32x2 fv[4]; unpack8v(u, fv);
        f32x2 p = fd2[0] * fv[0];
#pragma unroll
        for (int k = 1; k < 4; ++k) p += fd2[k] * fv[k];
        float q = p.x + p.y;
        q += __shfl_xor(q, 1);
        float w = act ? EXP2(q) : 0.f;
        f32x2 W = (f32x2){w, w};
#pragma unroll
        for (int k = 0; k < 4; ++k) acc2[k] += W * fv[k];
        l += w;
    }
    // cross-group merge (pure sums)
#pragma unroll
    for (int off = 16; off <= 32; off <<= 1) {
        l += __shfl_xor(l, off);
#pragma unroll
        for (int k = 0; k < 4; ++k) {
            acc2[k].x += __shfl_xor(acc2[k].x, off);
            acc2[k].y += __shfl_xor(acc2[k].y, off);
        }
    }
    if (grp == 0) {
        float rcp = 1.f / fmaxf(l, 1e-9f);
        float v[8];
#pragma unroll
        for (int k = 0; k < 4; ++k) {
            float x0 = acc2[k].x * rcp;
            float x1 = acc2[k].y * rcp;
            v[2 * k]     = (x0 > 0.f) ? x0 : expm1f(x0);   // ELU fused
            v[2 * k + 1] = (x1 > 0.f) ? x1 : expm1f(x1);
        }
        uint4 pk;
        pk.x = (unsigned)f32_to_bf16_raw(v[0]) | ((unsigned)f32_to_bf16_raw(v[1]) << 16);
        pk.y = (unsigned)f32_to_bf16_raw(v[2]) | ((unsigned)f32_to_bf16_raw(v[3]) << 16);
        pk.z = (unsigned)f32_to_bf16_raw(v[4]) | ((unsigned)f32_to_bf16_raw(v[5]) << 16);
        pk.w = (unsigned)f32_to_bf16_raw(v[6]) | ((unsigned)f32_to_bf16_raw(v[7]) << 16);
        *(uint4*)(agg1e + (size_t)wave * 128 + gl * 8) = pk;
    }
}

// ======= layer 2 fused GAT (R18 = R14 structure + software pipeline) =======
// Wave = 1 dst; 8 groups x 8 lanes; lane = 8 dims (1 uint4);
// 64-dim dot via 3 intra-group shfls; prefetched like gat1.
#define GAT2_PROC(U0, U1)                                                     \
    {                                                                         \
        f32x2 f0[4], f1[4];                                                   \
        unpack8v(U0, f0); unpack8v(U1, f1);                                   \
        f32x2 p0 = fd2[0] * f0[0];                                            \
        f32x2 p1 = fd2[0] * f1[0];                                            \
        _Pragma("unroll")                                                     \
        for (int k = 1; k < 4; ++k) { p0 += fd2[k] * f0[k]; p1 += fd2[k] * f1[k]; } \
        float q0 = p0.x + p0.y, q1 = p1.x + p1.y;                             \
        q0 += __shfl_xor(q0, 1); q1 += __shfl_xor(q1, 1);                     \
        q0 += __shfl_xor(q0, 2); q1 += __shfl_xor(q1, 2);                     \
        q0 += __shfl_xor(q0, 4); q1 += __shfl_xor(q1, 4);                     \
        float w0 = EXP2(q0), w1 = EXP2(q1);                                   \
        f32x2 W0 = (f32x2){w0, w0}, W1 = (f32x2){w1, w1};                     \
        _Pragma("unroll")                                                     \
        for (int k = 0; k < 4; ++k) { acc2[k] += W0 * f0[k]; acc2[k] += W1 * f1[k]; } \
        l += w0 + w1;                                                         \
    }

__global__ void gat2_kernel(const unsigned short* __restrict__ feat2,
                            const int* __restrict__ csr_src,
                            const int* __restrict__ start,
                            void* __restrict__ out, int N,
                            const int* __restrict__ flag) {
    int wave = blockIdx.x * 4 + (threadIdx.x >> 6);
    if (wave >= N) return;
    int lane = threadIdx.x & 63;
    int grp = lane >> 3, gl = lane & 7;
    const int f = *flag;
    const char* fb = (const char*)feat2;       // uniform base; row = 128 B
    unsigned loff = (unsigned)gl << 4;
    f32x2 fd2[4];
    unpack8v(*(const uint4*)(fb + (((unsigned)wave << 7) + loff)), fd2);
    const float SC = 0.125f * LOG2E;
    const f32x2 SC2 = (f32x2){SC, SC};
#pragma unroll
    for (int k = 0; k < 4; ++k) fd2[k] *= SC2;

    float l = 0.f;
    f32x2 acc2[4];
#pragma unroll
    for (int k = 0; k < 4; ++k) acc2[k] = (f32x2){0.f, 0.f};

    int e0 = start[wave], e1 = start[wave + 1];
    int nfull = (e1 - e0) >> 4;                // full 16-edge iterations
    int base = e0;
    uint4 u0, u1;
    if (nfull > 0) {
        int s0 = csr_src[base + grp];
        int s1 = csr_src[base + 8 + grp];
        u0 = *(const uint4*)(fb + (((unsigned)s0 << 7) + loff));
        u1 = *(const uint4*)(fb + (((unsigned)s1 << 7) + loff));
    }
    for (int it = 0; it < nfull - 1; ++it) {
        int nb = base + 16;
        int s0 = csr_src[nb + grp];
        int s1 = csr_src[nb + 8 + grp];
        uint4 n0 = *(const uint4*)(fb + (((unsigned)s0 << 7) + loff));
        uint4 n1 = *(const uint4*)(fb + (((unsigned)s1 << 7) + loff));
        GAT2_PROC(u0, u1);
        u0 = n0; u1 = n1; base = nb;
    }
    if (nfull > 0) { GAT2_PROC(u0, u1); base += 16; }
    for (; base < e1; base += 8) {
        int ed = base + grp;
        bool act = ed < e1;
        int s = act ? csr_src[ed] : 0;
        uint4 u = *(const uint4*)(fb + (((unsigned)s << 7) + loff));
        f32x2 fv[4]; unpack8v(u, fv);
        f32x2 p = fd2[0] * fv[0];
#pragma unroll
        for (int k = 1; k < 4; ++k) p += fd2[k] * fv[k];
        float q = p.x + p.y;
        q += __shfl_xor(q, 1);
        q += __shfl_xor(q, 2);
        q += __shfl_xor(q, 4);
        float w = act ? EXP2(q) : 0.f;
        f32x2 W = (f32x2){w, w};
#pragma unroll
        for (int k = 0; k < 4; ++k) acc2[k] += W * fv[k];
        l += w;
    }
#pragma unroll
    for (int off = 8; off <= 32; off <<= 1) {
        l += __shfl_xor(l, off);
#pragma unroll
        for (int k = 0; k < 4; ++k) {
            acc2[k].x += __shfl_xor(acc2[k].x, off);
            acc2[k].y += __shfl_xor(acc2[k].y, off);
        }
    }
    if (grp == 0) {
        float rcp = 1.f / fmaxf(l, 1e-9f);
        float v[8];
#pragma unroll
        for (int k = 0; k < 4; ++k) {
            v[2 * k]     = acc2[k].x * rcp;
            v[2 * k + 1] = acc2[k].y * rcp;
        }
        if (f) {
            float* op = (float*)out + (size_t)wave * 64 + gl * 8;
            *(float4*)(op)     = (float4){v[0], v[1], v[2], v[3]};
            *(float4*)(op + 4) = (float4){v[4], v[5], v[6], v[7]};
        } else {
            uint4 pk;
            pk.x = (unsigned)f32_to_bf16_raw(v[0]) | ((unsigned)f32_to_bf16_raw(v[1]) << 16);
            pk.y = (unsigned)f32_to_bf16_raw(v[2]) | ((unsigned)f32_to_bf16_raw(v[3]) << 16);
            pk.z = (unsigned)f32_to_bf16_raw(v[4]) | ((unsigned)f32_to_bf16_raw(v[5]) << 16);
            pk.w = (unsigned)f32_to_bf16_raw(v[6]) | ((unsigned)f32_to_bf16_raw(v[7]) << 16);
            *(uint4*)((unsigned short*)out + (size_t)wave * 64 + gl * 8) = pk;
        }
    }
}

extern "C" void kernel_launch(void* const* d_in, const int* in_sizes, int n_in,
                              void* d_out, int out_size, void* d_ws, size_t ws_size,
                              hipStream_t stream) {
    const void* h  = d_in[0];
    const void* W1 = d_in[1];
    const void* W2 = d_in[2];
    const int* src = (const int*)d_in[3];
    const int* dst = (const int*)d_in[4];

    float* ws = (float*)d_ws;
    // Layout (4-byte words), peak ~45.5 MB.
    unsigned short* feat1 = (unsigned short*)ws;
    unsigned short* agg1e = (unsigned short*)(ws + 3200000);
    unsigned short* feat2 = (unsigned short*)ws;      // after feat1 dead
    unsigned* inter       = (unsigned*)(ws + 6400000);
    int*   csr_src        = (int*)(ws + 9600000);
    int*   start          = (int*)(ws + 11200000);
    int*   flag           = (int*)(ws + 11330000);
    int*   bcnt           = (int*)(ws + 11331000);
    int*   bbase          = (int*)(ws + 11332000);
    int*   bcur           = (int*)(ws + 11333000);
    unsigned short* W1T   = (unsigned short*)(ws + 11340000);
    unsigned short* W2T   = (unsigned short*)(ws + 11350000);

    detect_dtype_kernel<<<1, 256, 0, stream>>>((const unsigned short*)W1, flag, bcnt);
    prep_kernel<<<12, 256, 0, stream>>>(W1, W2, W1T, W2T, flag);

    // ---- binned CSR build (by dst), storing src ids ----
    bucket_count_kernel<<<NB_A, 256, 0, stream>>>(dst, bcnt, N_EDGES);
    bucket_scan_kernel<<<1, 128, 0, stream>>>(bcnt, bbase, bcur);
    binA_kernel<<<NB_A, 256, 0, stream>>>(src, dst, bcur, inter, N_EDGES);
    binB_kernel<<<NBUCK, 256, 0, stream>>>(inter, bbase, csr_src, start, N_NODES, N_EDGES);

    gemm1_mfma_kernel<<<(N_NODES + 63) / 64, 256, 0, stream>>>(h, W1T, feat1, N_NODES, flag);
    gat1_kernel<<<(N_NODES + 3) / 4, 256, 0, stream>>>(feat1, csr_src, start, agg1e, N_NODES);
    gemm2_mfma_kernel<<<(N_NODES + 63) / 64, 256, 0, stream>>>(agg1e, W2T, feat2, N_NODES);
    gat2_kernel<<<(N_NODES + 3) / 4, 256, 0, stream>>>(feat2, csr_src, start, d_out, N_NODES, flag);
}

// Round 6
// 245.442 us; speedup vs baseline: 1.2048x; 1.1615x over previous
//
#include <hip/hip_runtime.h>
#include <hip/hip_bf16.h>

#define N_NODES 50000
#define N_EDGES 1600000
#define EPB 4096              // edges per binning block
#define NB_A ((N_EDGES + EPB - 1) / EPB)   // 391 edge-chunk blocks
#define NBUCK2 391            // ceil(50000/128) buckets of 128 nodes
#define BSHIFT 7
#define BMASK 127

typedef short bf16x8 __attribute__((ext_vector_type(8)));
typedef float f32x4  __attribute__((ext_vector_type(4)));
typedef float f32x2  __attribute__((ext_vector_type(2)));

#if __has_builtin(__builtin_amdgcn_exp2f)
#define EXP2(x) __builtin_amdgcn_exp2f(x)
#else
#define EXP2(x) exp2f(x)
#endif
#define LOG2E 1.44269504088896340736f

__device__ __forceinline__ float bf16_raw_to_f32(unsigned short u) {
    return __uint_as_float(((unsigned)u) << 16);
}
__device__ __forceinline__ unsigned short f32_to_bf16_raw(float v) {
    unsigned u = __float_as_uint(v);
    return (unsigned short)((u + 0x7fffu + ((u >> 16) & 1u)) >> 16);
}
__device__ __forceinline__ float load_elem(const void* p, size_t i, int f) {
    if (f) return ((const float*)p)[i];
    return bf16_raw_to_f32(((const unsigned short*)p)[i]);
}
// unpack 8 bf16 into 4 float2 pairs (pair k = dims {2k, 2k+1})
__device__ __forceinline__ void unpack8v(uint4 u, f32x2* f) {
    f[0] = (f32x2){__uint_as_float(u.x << 16), __uint_as_float(u.x & 0xffff0000u)};
    f[1] = (f32x2){__uint_as_float(u.y << 16), __uint_as_float(u.y & 0xffff0000u)};
    f[2] = (f32x2){__uint_as_float(u.z << 16), __uint_as_float(u.z & 0xffff0000u)};
    f[3] = (f32x2){__uint_as_float(u.w << 16), __uint_as_float(u.w & 0xffff0000u)};
}

// in-block dtype detect (R4-verified heuristic: fp32 storage looks like
// huge/NaN values when read as bf16 pairs). All threads return the flag.
__device__ __forceinline__ int block_detect(const unsigned short* w1raw) {
    __shared__ float red[256];
    int t = threadIdx.x;
    float mx = 0.f;
    for (int i = t * 2; i < 16384; i += 512) {
        float v = fabsf(bf16_raw_to_f32(w1raw[i]));
        if (!isnan(v)) mx = fmaxf(mx, v);
    }
    red[t] = mx;
    __syncthreads();
    for (int s = 128; s > 0; s >>= 1) {
        if (t < s) red[t] = fmaxf(red[t], red[t + s]);
        __syncthreads();
    }
    return (red[0] > 1e4f) ? 1 : 0;
}

#define WPAD 136

// ===== K1: fused [bucket_count (391) | prep (12) | detect (1)] =====
__global__ void k1_count_prep_kernel(const int* __restrict__ dst, int E,
                                     int* __restrict__ bcnt,
                                     const void* __restrict__ W1,
                                     const void* __restrict__ W2,
                                     unsigned short* __restrict__ W1T,
                                     unsigned short* __restrict__ W2T,
                                     int* __restrict__ flag) {
    int bid = blockIdx.x;
    if (bid < NB_A) {
        // ---- bucket histogram over 128-node buckets ----
        __shared__ int hist[NBUCK2];
        int t = threadIdx.x;
        for (int i = t; i < NBUCK2; i += 256) hist[i] = 0;
        __syncthreads();
        int e0 = bid * EPB;
        for (int k = 0; k < 16; ++k) {
            int e = e0 + k * 256 + t;
            if (e < E) atomicAdd(&hist[dst[e] >> BSHIFT], 1);
        }
        __syncthreads();
        for (int i = t; i < NBUCK2; i += 256)
            if (hist[i]) atomicAdd(&bcnt[i], hist[i]);
    } else if (bid < NB_A + 12) {
        // ---- weight transpose prep (self-detecting dtype) ----
        const int f = block_detect((const unsigned short*)W1);
        int b2 = bid - NB_A, tid = threadIdx.x;
        if (b2 < 8) {
            int n = b2 * 16 + (tid & 15);
            int kb = (tid >> 4) * 8;
            for (int j = 0; j < 8; ++j)
                W1T[n * WPAD + kb + j] = f32_to_bf16_raw(load_elem(W1, (size_t)(kb + j) * 128 + n, f));
        } else {
            int n = (b2 - 8) * 16 + (tid & 15);
            int kb = (tid >> 4) * 8;
            for (int j = 0; j < 8; ++j)
                W2T[n * WPAD + kb + j] = f32_to_bf16_raw(load_elem(W2, (size_t)(kb + j) * 64 + n, f));
        }
    } else {
        int f = block_detect((const unsigned short*)W1);
        if (threadIdx.x == 0) flag[0] = f;
    }
}

// ---- MFMA GEMM1 body (R9-proven), with row base for split launches ----
__device__ __forceinline__ void gemm1_body(const void* __restrict__ h,
                                           const unsigned short* __restrict__ W1T,
                                           unsigned short* __restrict__ feat1, int N,
                                           int f, int blk, int row_base) {
    int lane = threadIdx.x & 63;
    int rbase = row_base + blk * 64 + (threadIdx.x >> 6) * 16;
    int arow = rbase + (lane & 15);
    int arowc = min(arow, N - 1);
    int kb0 = (lane >> 4) * 8;

    f32x4 acc[8];
#pragma unroll
    for (int t = 0; t < 8; ++t) acc[t] = (f32x4){0.f, 0.f, 0.f, 0.f};

#pragma unroll
    for (int ks = 0; ks < 4; ++ks) {
        int kb = ks * 32 + kb0;
        bf16x8 afrag;
        if (f == 0) {
            afrag = *(const bf16x8*)((const unsigned short*)h + (size_t)arowc * 128 + kb);
        } else {
            const float* hp = (const float*)h + (size_t)arowc * 128 + kb;
#pragma unroll
            for (int j = 0; j < 8; ++j) afrag[j] = (short)f32_to_bf16_raw(hp[j]);
        }
#pragma unroll
        for (int t = 0; t < 8; ++t) {
            int n = t * 16 + (lane & 15);
            bf16x8 bfrag = *(const bf16x8*)(W1T + n * WPAD + kb);
            acc[t] = __builtin_amdgcn_mfma_f32_16x16x32_bf16(afrag, bfrag, acc[t], 0, 0, 0);
        }
    }
    int orow0 = rbase + (lane >> 4) * 4;
    int col = lane & 15;
#pragma unroll
    for (int t = 0; t < 8; ++t)
#pragma unroll
        for (int r = 0; r < 4; ++r) {
            int row = orow0 + r;
            if (row < N)
                feat1[(size_t)row * 128 + t * 16 + col] = f32_to_bf16_raw(acc[t][r]);
        }
}

#define G1LO 391                   // gemm1 blocks covering rows [0, 25024)
#define G1OFF (G1LO * 64)          // 25024

// ===== K2: fused [binA (391) | gemm1 rows 0..25023 (391)] =====
__global__ void k2_binA_gemm1lo_kernel(const int* __restrict__ src,
                                       const int* __restrict__ dst,
                                       const int* __restrict__ bcnt,
                                       int* __restrict__ bcur,
                                       unsigned* __restrict__ inter, int E,
                                       const void* __restrict__ h,
                                       const unsigned short* __restrict__ W1T,
                                       unsigned short* __restrict__ feat1, int N,
                                       const int* __restrict__ flag) {
    int bid = blockIdx.x;
    if (bid >= NB_A) {
        gemm1_body(h, W1T, feat1, N, *flag, bid - NB_A, 0);
        return;
    }
    __shared__ int hist[NBUCK2], P[NBUCK2], cur[NBUCK2];
    __shared__ int sc2[256];
    int t = threadIdx.x;
    for (int i = t; i < NBUCK2; i += 256) { hist[i] = 0; cur[i] = 0; }
    __syncthreads();
    int e0 = bid * EPB;
    for (int k = 0; k < 16; ++k) {
        int e = e0 + k * 256 + t;
        if (e < E) atomicAdd(&hist[dst[e] >> BSHIFT], 1);
    }
    // local exclusive scan of bcnt (pair-per-thread, 391 entries)
    int i0 = 2 * t, i1 = 2 * t + 1;
    int v0 = (i0 < NBUCK2) ? bcnt[i0] : 0;
    int v1 = (i1 < NBUCK2) ? bcnt[i1] : 0;
    sc2[t] = v0 + v1;
    __syncthreads();                      // also publishes hist atomics
    for (int off = 1; off < 256; off <<= 1) {
        int x = (t >= off) ? sc2[t - off] : 0;
        __syncthreads();
        sc2[t] += x;
        __syncthreads();
    }
    int exclp = sc2[t] - v0 - v1;
    if (i0 < NBUCK2) P[i0] = exclp;
    if (i1 < NBUCK2) P[i1] = exclp + v0;
    __syncthreads();
    for (int i = t; i < NBUCK2; i += 256) {
        int hv = hist[i];
        if (hv) P[i] += atomicAdd(&bcur[i], hv);
    }
    __syncthreads();
    for (int k = 0; k < 16; ++k) {
        int e = e0 + k * 256 + t;
        if (e < E) {
            int d = dst[e];
            int b = d >> BSHIFT;
            int off = atomicAdd(&cur[b], 1);
            inter[P[b] + off] = (unsigned)src[e] | ((unsigned)(d & BMASK) << 16);
        }
    }
}

// ===== K3: fused [binB (391) | gemm1 rows 25024..49999 (391)] =====
__global__ void k3_binB_gemm1hi_kernel(const unsigned* __restrict__ inter,
                                       const int* __restrict__ bcnt,
                                       int* __restrict__ csr_src,
                                       int* __restrict__ start,
                                       int N, int E,
                                       const void* __restrict__ h,
                                       const unsigned short* __restrict__ W1T,
                                       unsigned short* __restrict__ feat1,
                                       const int* __restrict__ flag) {
    int bid = blockIdx.x;
    if (bid >= NBUCK2) {
        gemm1_body(h, W1T, feat1, N, *flag, bid - NBUCK2, G1OFF);
        return;
    }
    int b = bid;
    int node0 = b << BSHIFT;
    __shared__ int red[256];
    __shared__ int hist[128];
    __shared__ int tmp[128];
    int t = threadIdx.x;
    // lo = sum bcnt[0..b)
    int part = 0;
    for (int i = t; i < b; i += 256) part += bcnt[i];
    red[t] = part;
    __syncthreads();
    for (int s = 128; s > 0; s >>= 1) {
        if (t < s) red[t] += red[t + s];
        __syncthreads();
    }
    int lo = red[0];
    int hi = lo + bcnt[b];
    if (t < 128) hist[t] = 0;
    __syncthreads();
    for (int e = lo + t; e < hi; e += 256) atomicAdd(&hist[inter[e] >> 16], 1);
    __syncthreads();
    int own = (t < 128) ? hist[t] : 0;
    if (t < 128) tmp[t] = own;
    __syncthreads();
    for (int off = 1; off < 128; off <<= 1) {
        int x = (t >= off && t < 128) ? tmp[t - off] : 0;
        __syncthreads();
        if (t < 128) tmp[t] += x;
        __syncthreads();
    }
    int nodeCnt = min(128, N - node0);
    if (t < nodeCnt) start[node0 + t] = lo + (tmp[t] - own);
    if (t < 128) hist[t] = lo + (tmp[t] - own);   // scatter cursor
    if (b == NBUCK2 - 1 && t == 0) start[N] = E;
    __syncthreads();
    for (int e = lo + t; e < hi; e += 256) {
        unsigned u = inter[e];
        int slot = atomicAdd(&hist[u >> 16], 1);
        csr_src[slot] = (int)(u & 0xffffu);
    }
}

// ---- MFMA GEMM2 (R9-proven) ----
__global__ void gemm2_mfma_kernel(const unsigned short* __restrict__ agg1e,
                                  const unsigned short* __restrict__ W2T,
                                  unsigned short* __restrict__ feat2, int N) {
    int lane = threadIdx.x & 63;
    int rbase = blockIdx.x * 64 + (threadIdx.x >> 6) * 16;
    int arow = rbase + (lane & 15);
    int arowc = min(arow, N - 1);
    int kb0 = (lane >> 4) * 8;

    f32x4 acc[4];
#pragma unroll
    for (int t = 0; t < 4; ++t) acc[t] = (f32x4){0.f, 0.f, 0.f, 0.f};

#pragma unroll
    for (int ks = 0; ks < 4; ++ks) {
        int kb = ks * 32 + kb0;
        bf16x8 afrag = *(const bf16x8*)(agg1e + (size_t)arowc * 128 + kb);
#pragma unroll
        for (int t = 0; t < 4; ++t) {
            int n = t * 16 + (lane & 15);
            bf16x8 bfrag = *(const bf16x8*)(W2T + n * WPAD + kb);
            acc[t] = __builtin_amdgcn_mfma_f32_16x16x32_bf16(afrag, bfrag, acc[t], 0, 0, 0);
        }
    }
    int orow0 = rbase + (lane >> 4) * 4;
    int col = lane & 15;
#pragma unroll
    for (int t = 0; t < 4; ++t)
#pragma unroll
        for (int r = 0; r < 4; ++r) {
            int row = orow0 + r;
            if (row < N)
                feat2[(size_t)row * 64 + t * 16 + col] = f32_to_bf16_raw(acc[t][r]);
        }
}

// ======= layer 1 fused GAT (R18-proven body, unchanged) =======
#define GAT1_PROC(U0, U1)                                                     \
    {                                                                         \
        f32x2 f0[4], f1[4];                                                   \
        unpack8v(U0, f0); unpack8v(U1, f1);                                   \
        f32x2 p0 = fd2[0] * f0[0];                                            \
        f32x2 p1 = fd2[0] * f1[0];                                            \
        _Pragma("unroll")                                                     \
        for (int k = 1; k < 4; ++k) { p0 += fd2[k] * f0[k]; p1 += fd2[k] * f1[k]; } \
        float q0 = p0.x + p0.y, q1 = p1.x + p1.y;                             \
        q0 += __shfl_xor(q0, 1); q1 += __shfl_xor(q1, 1);                     \
        float w0 = EXP2(q0), w1 = EXP2(q1);                                   \
        f32x2 W0 = (f32x2){w0, w0}, W1 = (f32x2){w1, w1};                     \
        _Pragma("unroll")                                                     \
        for (int k = 0; k < 4; ++k) { acc2[k] += W0 * f0[k]; acc2[k] += W1 * f1[k]; } \
        l += w0 + w1;                                                         \
    }

__global__ void gat1_kernel(const unsigned short* __restrict__ feat1,
                            const int* __restrict__ csr_src,
                            const int* __restrict__ start,
                            unsigned short* __restrict__ agg1e, int N) {
    int wave = blockIdx.x * 4 + (threadIdx.x >> 6);
    if (wave >= N) return;
    int lane = threadIdx.x & 63;
    int grp = lane >> 4, gl = lane & 15;
    const char* fb = (const char*)feat1;       // uniform base; row = 256 B
    unsigned loff = (unsigned)gl << 4;
    f32x2 fd2[4];
    unpack8v(*(const uint4*)(fb + (((unsigned)wave << 8) + loff)), fd2);
    const float SC = 0.25f * LOG2E;            // fold score scale + log2e
    const f32x2 SC2 = (f32x2){SC, SC};
#pragma unroll
    for (int k = 0; k < 4; ++k) fd2[k] *= SC2;

    float l = 0.f;
    f32x2 acc2[4];
#pragma unroll
    for (int k = 0; k < 4; ++k) acc2[k] = (f32x2){0.f, 0.f};

    int e0 = start[wave], e1 = start[wave + 1];
    int nfull = (e1 - e0) >> 3;                // full 8-edge iterations
    int base = e0;
    uint4 u0, u1;
    if (nfull > 0) {
        int s0 = csr_src[base + grp];
        int s1 = csr_src[base + 4 + grp];
        u0 = *(const uint4*)(fb + (((unsigned)s0 << 8) + loff));
        u1 = *(const uint4*)(fb + (((unsigned)s1 << 8) + loff));
    }
    for (int it = 0; it < nfull - 1; ++it) {   // pipelined: prefetch iter+1
        int nb = base + 8;
        int s0 = csr_src[nb + grp];
        int s1 = csr_src[nb + 4 + grp];
        uint4 n0 = *(const uint4*)(fb + (((unsigned)s0 << 8) + loff));
        uint4 n1 = *(const uint4*)(fb + (((unsigned)s1 << 8) + loff));
        GAT1_PROC(u0, u1);
        u0 = n0; u1 = n1; base = nb;
    }
    if (nfull > 0) { GAT1_PROC(u0, u1); base += 8; }
    for (; base < e1; base += 4) {             // masked tail, 4 edges/step
        int ed = base + grp;
        bool act = ed < e1;
        int s = act ? csr_src[ed] : 0;
        uint4 u = *(const uint4*)(fb + (((unsigned)s << 8) + loff));
        f32x2 fv[4]; unpack8v(u, fv);
        f32x2 p = fd2[0] * fv[0];
#pragma unroll
        for (int k = 1; k < 4; ++k) p += fd2[k] * fv[k];
        float q = p.x + p.y;
        q += __shfl_xor(q, 1);
        float w = act ? EXP2(q) : 0.f;
        f32x2 W = (f32x2){w, w};
#pragma unroll
        for (int k = 0; k < 4; ++k) acc2[k] += W * fv[k];
        l += w;
    }
    // cross-group merge (pure sums)
#pragma unroll
    for (int off = 16; off <= 32; off <<= 1) {
        l += __shfl_xor(l, off);
#pragma unroll
        for (int k = 0; k < 4; ++k) {
            acc2[k].x += __shfl_xor(acc2[k].x, off);
            acc2[k].y += __shfl_xor(acc2[k].y, off);
        }
    }
    if (grp == 0) {
        float rcp = 1.f / fmaxf(l, 1e-9f);
        float v[8];
#pragma unroll
        for (int k = 0; k < 4; ++k) {
            float x0 = acc2[k].x * rcp;
            float x1 = acc2[k].y * rcp;
            v[2 * k]     = (x0 > 0.f) ? x0 : expm1f(x0);   // ELU fused
            v[2 * k + 1] = (x1 > 0.f) ? x1 : expm1f(x1);
        }
        uint4 pk;
        pk.x = (unsigned)f32_to_bf16_raw(v[0]) | ((unsigned)f32_to_bf16_raw(v[1]) << 16);
        pk.y = (unsigned)f32_to_bf16_raw(v[2]) | ((unsigned)f32_to_bf16_raw(v[3]) << 16);
        pk.z = (unsigned)f32_to_bf16_raw(v[4]) | ((unsigned)f32_to_bf16_raw(v[5]) << 16);
        pk.w = (unsigned)f32_to_bf16_raw(v[6]) | ((unsigned)f32_to_bf16_raw(v[7]) << 16);
        *(uint4*)(agg1e + (size_t)wave * 128 + gl * 8) = pk;
    }
}

// ======= layer 2 fused GAT (R18-proven body, unchanged) =======
#define GAT2_PROC(U0, U1)                                                     \
    {                                                                         \
        f32x2 f0[4], f1[4];                                                   \
        unpack8v(U0, f0); unpack8v(U1, f1);                                   \
        f32x2 p0 = fd2[0] * f0[0];                                            \
        f32x2 p1 = fd2[0] * f1[0];                                            \
        _Pragma("unroll")                                                     \
        for (int k = 1; k < 4; ++k) { p0 += fd2[k] * f0[k]; p1 += fd2[k] * f1[k]; } \
        float q0 = p0.x + p0.y, q1 = p1.x + p1.y;                             \
        q0 += __shfl_xor(q0, 1); q1 += __shfl_xor(q1, 1);                     \
        q0 += __shfl_xor(q0, 2); q1 += __shfl_xor(q1, 2);                     \
        q0 += __shfl_xor(q0, 4); q1 += __shfl_xor(q1, 4);                     \
        float w0 = EXP2(q0), w1 = EXP2(q1);                                   \
        f32x2 W0 = (f32x2){w0, w0}, W1 = (f32x2){w1, w1};                     \
        _Pragma("unroll")                                                     \
        for (int k = 0; k < 4; ++k) { acc2[k] += W0 * f0[k]; acc2[k] += W1 * f1[k]; } \
        l += w0 + w1;                                                         \
    }

__global__ void gat2_kernel(const unsigned short* __restrict__ feat2,
                            const int* __restrict__ csr_src,
                            const int* __restrict__ start,
                            void* __restrict__ out, int N,
                            const int* __restrict__ flag) {
    int wave = blockIdx.x * 4 + (threadIdx.x >> 6);
    if (wave >= N) return;
    int lane = threadIdx.x & 63;
    int grp = lane >> 3, gl = lane & 7;
    const int f = *flag;
    const char* fb = (const char*)feat2;       // uniform base; row = 128 B
    unsigned loff = (unsigned)gl << 4;
    f32x2 fd2[4];
    unpack8v(*(const uint4*)(fb + (((unsigned)wave << 7) + loff)), fd2);
    const float SC = 0.125f * LOG2E;
    const f32x2 SC2 = (f32x2){SC, SC};
#pragma unroll
    for (int k = 0; k < 4; ++k) fd2[k] *= SC2;

    float l = 0.f;
    f32x2 acc2[4];
#pragma unroll
    for (int k = 0; k < 4; ++k) acc2[k] = (f32x2){0.f, 0.f};

    int e0 = start[wave], e1 = start[wave + 1];
    int nfull = (e1 - e0) >> 4;                // full 16-edge iterations
    int base = e0;
    uint4 u0, u1;
    if (nfull > 0) {
        int s0 = csr_src[base + grp];
        int s1 = csr_src[base + 8 + grp];
        u0 = *(const uint4*)(fb + (((unsigned)s0 << 7) + loff));
        u1 = *(const uint4*)(fb + (((unsigned)s1 << 7) + loff));
    }
    for (int it = 0; it < nfull - 1; ++it) {
        int nb = base + 16;
        int s0 = csr_src[nb + grp];
        int s1 = csr_src[nb + 8 + grp];
        uint4 n0 = *(const uint4*)(fb + (((unsigned)s0 << 7) + loff));
        uint4 n1 = *(const uint4*)(fb + (((unsigned)s1 << 7) + loff));
        GAT2_PROC(u0, u1);
        u0 = n0; u1 = n1; base = nb;
    }
    if (nfull > 0) { GAT2_PROC(u0, u1); base += 16; }
    for (; base < e1; base += 8) {
        int ed = base + grp;
        bool act = ed < e1;
        int s = act ? csr_src[ed] : 0;
        uint4 u = *(const uint4*)(fb + (((unsigned)s << 7) + loff));
        f32x2 fv[4]; unpack8v(u, fv);
        f32x2 p = fd2[0] * fv[0];
#pragma unroll
        for (int k = 1; k < 4; ++k) p += fd2[k] * fv[k];
        float q = p.x + p.y;
        q += __shfl_xor(q, 1);
        q += __shfl_xor(q, 2);
        q += __shfl_xor(q, 4);
        float w = act ? EXP2(q) : 0.f;
        f32x2 W = (f32x2){w, w};
#pragma unroll
        for (int k = 0; k < 4; ++k) acc2[k] += W * fv[k];
        l += w;
    }
#pragma unroll
    for (int off = 8; off <= 32; off <<= 1) {
        l += __shfl_xor(l, off);
#pragma unroll
        for (int k = 0; k < 4; ++k) {
            acc2[k].x += __shfl_xor(acc2[k].x, off);
            acc2[k].y += __shfl_xor(acc2[k].y, off);
        }
    }
    if (grp == 0) {
        float rcp = 1.f / fmaxf(l, 1e-9f);
        float v[8];
#pragma unroll
        for (int k = 0; k < 4; ++k) {
            v[2 * k]     = acc2[k].x * rcp;
            v[2 * k + 1] = acc2[k].y * rcp;
        }
        if (f) {
            float* op = (float*)out + (size_t)wave * 64 + gl * 8;
            *(float4*)(op)     = (float4){v[0], v[1], v[2], v[3]};
            *(float4*)(op + 4) = (float4){v[4], v[5], v[6], v[7]};
        } else {
            uint4 pk;
            pk.x = (unsigned)f32_to_bf16_raw(v[0]) | ((unsigned)f32_to_bf16_raw(v[1]) << 16);
            pk.y = (unsigned)f32_to_bf16_raw(v[2]) | ((unsigned)f32_to_bf16_raw(v[3]) << 16);
            pk.z = (unsigned)f32_to_bf16_raw(v[4]) | ((unsigned)f32_to_bf16_raw(v[5]) << 16);
            pk.w = (unsigned)f32_to_bf16_raw(v[6]) | ((unsigned)f32_to_bf16_raw(v[7]) << 16);
            *(uint4*)((unsigned short*)out + (size_t)wave * 64 + gl * 8) = pk;
        }
    }
}

extern "C" void kernel_launch(void* const* d_in, const int* in_sizes, int n_in,
                              void* d_out, int out_size, void* d_ws, size_t ws_size,
                              hipStream_t stream) {
    const void* h  = d_in[0];
    const void* W1 = d_in[1];
    const void* W2 = d_in[2];
    const int* src = (const int*)d_in[3];
    const int* dst = (const int*)d_in[4];

    float* ws = (float*)d_ws;
    // Layout (4-byte words), peak ~45.5 MB.
    unsigned short* feat1 = (unsigned short*)ws;
    unsigned short* agg1e = (unsigned short*)(ws + 3200000);
    unsigned short* feat2 = (unsigned short*)ws;      // after feat1 dead
    unsigned* inter       = (unsigned*)(ws + 6400000);
    int*   csr_src        = (int*)(ws + 9600000);
    int*   start          = (int*)(ws + 11200000);
    int*   flag           = (int*)(ws + 11330000);
    int*   bcnt           = (int*)(ws + 11331000);    // 391 ints
    int*   bcur           = bcnt + NBUCK2;            // 391 ints (contiguous)
    unsigned short* W1T   = (unsigned short*)(ws + 11340000);
    unsigned short* W2T   = (unsigned short*)(ws + 11350000);

    // zero bucket counters + cursors in one async memset (graph-safe)
    hipMemsetAsync(bcnt, 0, 2 * NBUCK2 * sizeof(int), stream);

    // K1: histogram | weight prep | dtype flag  (404 blocks)
    k1_count_prep_kernel<<<NB_A + 13, 256, 0, stream>>>(
        dst, N_EDGES, bcnt, W1, W2, W1T, W2T, flag);

    // K2: binA scatter-to-buckets | gemm1 rows [0, 25024)   (782 blocks)
    k2_binA_gemm1lo_kernel<<<NB_A + G1LO, 256, 0, stream>>>(
        src, dst, bcnt, bcur, inter, N_EDGES, h, W1T, feat1, N_NODES, flag);

    // K3: binB bucket->CSR | gemm1 rows [25024, 50000)      (782 blocks)
    k3_binB_gemm1hi_kernel<<<NBUCK2 + G1LO, 256, 0, stream>>>(
        inter, bcnt, csr_src, start, N_NODES, N_EDGES, h, W1T, feat1, flag);

    gat1_kernel<<<(N_NODES + 3) / 4, 256, 0, stream>>>(feat1, csr_src, start, agg1e, N_NODES);
    gemm2_mfma_kernel<<<(N_NODES + 63) / 64, 256, 0, stream>>>(agg1e, W2T, feat2, N_NODES);
    gat2_kernel<<<(N_NODES + 3) / 4, 256, 0, stream>>>(feat2, csr_src, start, d_out, N_NODES, flag);
}

// Round 7
// 245.366 us; speedup vs baseline: 1.2052x; 1.0003x over previous
//
#include <hip/hip_runtime.h>
#include <hip/hip_bf16.h>

#define N_NODES 50000
#define N_EDGES 1600000
#define EPB 4096              // edges per binning block
#define NB_A ((N_EDGES + EPB - 1) / EPB)   // 391 edge-chunk blocks
#define NBUCK2 391            // ceil(50000/128) buckets of 128 nodes
#define BSHIFT 7
#define BMASK 127

typedef short bf16x8 __attribute__((ext_vector_type(8)));
typedef float f32x4  __attribute__((ext_vector_type(4)));
typedef float f32x2  __attribute__((ext_vector_type(2)));

#if __has_builtin(__builtin_amdgcn_exp2f)
#define EXP2(x) __builtin_amdgcn_exp2f(x)
#else
#define EXP2(x) exp2f(x)
#endif
#define LOG2E 1.44269504088896340736f

__device__ __forceinline__ float bf16_raw_to_f32(unsigned short u) {
    return __uint_as_float(((unsigned)u) << 16);
}
__device__ __forceinline__ unsigned short f32_to_bf16_raw(float v) {
    unsigned u = __float_as_uint(v);
    return (unsigned short)((u + 0x7fffu + ((u >> 16) & 1u)) >> 16);
}
__device__ __forceinline__ float load_elem(const void* p, size_t i, int f) {
    if (f) return ((const float*)p)[i];
    return bf16_raw_to_f32(((const unsigned short*)p)[i]);
}
// unpack 8 bf16 into 4 float2 pairs (pair k = dims {2k, 2k+1})
__device__ __forceinline__ void unpack8v(uint4 u, f32x2* f) {
    f[0] = (f32x2){__uint_as_float(u.x << 16), __uint_as_float(u.x & 0xffff0000u)};
    f[1] = (f32x2){__uint_as_float(u.y << 16), __uint_as_float(u.y & 0xffff0000u)};
    f[2] = (f32x2){__uint_as_float(u.z << 16), __uint_as_float(u.z & 0xffff0000u)};
    f[3] = (f32x2){__uint_as_float(u.w << 16), __uint_as_float(u.w & 0xffff0000u)};
}

// in-block dtype detect (R4-verified heuristic: fp32 storage looks like
// huge/NaN values when read as bf16 pairs). All threads return the flag.
__device__ __forceinline__ int block_detect(const unsigned short* w1raw) {
    __shared__ float red[256];
    int t = threadIdx.x;
    float mx = 0.f;
    for (int i = t * 2; i < 16384; i += 512) {
        float v = fabsf(bf16_raw_to_f32(w1raw[i]));
        if (!isnan(v)) mx = fmaxf(mx, v);
    }
    red[t] = mx;
    __syncthreads();
    for (int s = 128; s > 0; s >>= 1) {
        if (t < s) red[t] = fmaxf(red[t], red[t + s]);
        __syncthreads();
    }
    return (red[0] > 1e4f) ? 1 : 0;
}

#define WPAD 136

// ===== K1: fused [bucket_count (391) | prep (12) | detect (1)] =====
__global__ void k1_count_prep_kernel(const int* __restrict__ dst, int E,
                                     int* __restrict__ bcnt,
                                     const void* __restrict__ W1,
                                     const void* __restrict__ W2,
                                     unsigned short* __restrict__ W1T,
                                     unsigned short* __restrict__ W2T,
                                     int* __restrict__ flag) {
    int bid = blockIdx.x;
    if (bid < NB_A) {
        // ---- bucket histogram over 128-node buckets ----
        __shared__ int hist[NBUCK2];
        int t = threadIdx.x;
        for (int i = t; i < NBUCK2; i += 256) hist[i] = 0;
        __syncthreads();
        int e0 = bid * EPB;
        for (int k = 0; k < 16; ++k) {
            int e = e0 + k * 256 + t;
            if (e < E) atomicAdd(&hist[dst[e] >> BSHIFT], 1);
        }
        __syncthreads();
        for (int i = t; i < NBUCK2; i += 256)
            if (hist[i]) atomicAdd(&bcnt[i], hist[i]);
    } else if (bid < NB_A + 12) {
        // ---- weight transpose prep (self-detecting dtype) ----
        const int f = block_detect((const unsigned short*)W1);
        int b2 = bid - NB_A, tid = threadIdx.x;
        if (b2 < 8) {
            int n = b2 * 16 + (tid & 15);
            int kb = (tid >> 4) * 8;
            for (int j = 0; j < 8; ++j)
                W1T[n * WPAD + kb + j] = f32_to_bf16_raw(load_elem(W1, (size_t)(kb + j) * 128 + n, f));
        } else {
            int n = (b2 - 8) * 16 + (tid & 15);
            int kb = (tid >> 4) * 8;
            for (int j = 0; j < 8; ++j)
                W2T[n * WPAD + kb + j] = f32_to_bf16_raw(load_elem(W2, (size_t)(kb + j) * 64 + n, f));
        }
    } else {
        int f = block_detect((const unsigned short*)W1);
        if (threadIdx.x == 0) flag[0] = f;
    }
}

// ---- MFMA GEMM1 body (R9-proven), with row base for split launches ----
__device__ __forceinline__ void gemm1_body(const void* __restrict__ h,
                                           const unsigned short* __restrict__ W1T,
                                           unsigned short* __restrict__ feat1, int N,
                                           int f, int blk, int row_base) {
    int lane = threadIdx.x & 63;
    int rbase = row_base + blk * 64 + (threadIdx.x >> 6) * 16;
    int arow = rbase + (lane & 15);
    int arowc = min(arow, N - 1);
    int kb0 = (lane >> 4) * 8;

    f32x4 acc[8];
#pragma unroll
    for (int t = 0; t < 8; ++t) acc[t] = (f32x4){0.f, 0.f, 0.f, 0.f};

#pragma unroll
    for (int ks = 0; ks < 4; ++ks) {
        int kb = ks * 32 + kb0;
        bf16x8 afrag;
        if (f == 0) {
            afrag = *(const bf16x8*)((const unsigned short*)h + (size_t)arowc * 128 + kb);
        } else {
            const float* hp = (const float*)h + (size_t)arowc * 128 + kb;
#pragma unroll
            for (int j = 0; j < 8; ++j) afrag[j] = (short)f32_to_bf16_raw(hp[j]);
        }
#pragma unroll
        for (int t = 0; t < 8; ++t) {
            int n = t * 16 + (lane & 15);
            bf16x8 bfrag = *(const bf16x8*)(W1T + n * WPAD + kb);
            acc[t] = __builtin_amdgcn_mfma_f32_16x16x32_bf16(afrag, bfrag, acc[t], 0, 0, 0);
        }
    }
    int orow0 = rbase + (lane >> 4) * 4;
    int col = lane & 15;
#pragma unroll
    for (int t = 0; t < 8; ++t)
#pragma unroll
        for (int r = 0; r < 4; ++r) {
            int row = orow0 + r;
            if (row < N)
                feat1[(size_t)row * 128 + t * 16 + col] = f32_to_bf16_raw(acc[t][r]);
        }
}

#define G1LO 391                   // gemm1 blocks covering rows [0, 25024)
#define G1OFF (G1LO * 64)          // 25024

// ===== K2: fused [binA (391) | gemm1 rows 0..25023 (391)] =====
__global__ void k2_binA_gemm1lo_kernel(const int* __restrict__ src,
                                       const int* __restrict__ dst,
                                       const int* __restrict__ bcnt,
                                       int* __restrict__ bcur,
                                       unsigned* __restrict__ inter, int E,
                                       const void* __restrict__ h,
                                       const unsigned short* __restrict__ W1T,
                                       unsigned short* __restrict__ feat1, int N,
                                       const int* __restrict__ flag) {
    int bid = blockIdx.x;
    if (bid >= NB_A) {
        gemm1_body(h, W1T, feat1, N, *flag, bid - NB_A, 0);
        return;
    }
    __shared__ int hist[NBUCK2], P[NBUCK2], cur[NBUCK2];
    __shared__ int sc2[256];
    int t = threadIdx.x;
    for (int i = t; i < NBUCK2; i += 256) { hist[i] = 0; cur[i] = 0; }
    __syncthreads();
    int e0 = bid * EPB;
    for (int k = 0; k < 16; ++k) {
        int e = e0 + k * 256 + t;
        if (e < E) atomicAdd(&hist[dst[e] >> BSHIFT], 1);
    }
    // local exclusive scan of bcnt (pair-per-thread, 391 entries)
    int i0 = 2 * t, i1 = 2 * t + 1;
    int v0 = (i0 < NBUCK2) ? bcnt[i0] : 0;
    int v1 = (i1 < NBUCK2) ? bcnt[i1] : 0;
    sc2[t] = v0 + v1;
    __syncthreads();                      // also publishes hist atomics
    for (int off = 1; off < 256; off <<= 1) {
        int x = (t >= off) ? sc2[t - off] : 0;
        __syncthreads();
        sc2[t] += x;
        __syncthreads();
    }
    int exclp = sc2[t] - v0 - v1;
    if (i0 < NBUCK2) P[i0] = exclp;
    if (i1 < NBUCK2) P[i1] = exclp + v0;
    __syncthreads();
    for (int i = t; i < NBUCK2; i += 256) {
        int hv = hist[i];
        if (hv) P[i] += atomicAdd(&bcur[i], hv);
    }
    __syncthreads();
    for (int k = 0; k < 16; ++k) {
        int e = e0 + k * 256 + t;
        if (e < E) {
            int d = dst[e];
            int b = d >> BSHIFT;
            int off = atomicAdd(&cur[b], 1);
            inter[P[b] + off] = (unsigned)src[e] | ((unsigned)(d & BMASK) << 16);
        }
    }
}

// ===== K3: fused [binB (391) | gemm1 rows 25024..49999 (391)] =====
__global__ void k3_binB_gemm1hi_kernel(const unsigned* __restrict__ inter,
                                       const int* __restrict__ bcnt,
                                       int* __restrict__ csr_src,
                                       int* __restrict__ start,
                                       int N, int E,
                                       const void* __restrict__ h,
                                       const unsigned short* __restrict__ W1T,
                                       unsigned short* __restrict__ feat1,
                                       const int* __restrict__ flag) {
    int bid = blockIdx.x;
    if (bid >= NBUCK2) {
        gemm1_body(h, W1T, feat1, N, *flag, bid - NBUCK2, G1OFF);
        return;
    }
    int b = bid;
    int node0 = b << BSHIFT;
    __shared__ int red[256];
    __shared__ int hist[128];
    __shared__ int tmp[128];
    int t = threadIdx.x;
    // lo = sum bcnt[0..b)
    int part = 0;
    for (int i = t; i < b; i += 256) part += bcnt[i];
    red[t] = part;
    __syncthreads();
    for (int s = 128; s > 0; s >>= 1) {
        if (t < s) red[t] += red[t + s];
        __syncthreads();
    }
    int lo = red[0];
    int hi = lo + bcnt[b];
    if (t < 128) hist[t] = 0;
    __syncthreads();
    for (int e = lo + t; e < hi; e += 256) atomicAdd(&hist[inter[e] >> 16], 1);
    __syncthreads();
    int own = (t < 128) ? hist[t] : 0;
    if (t < 128) tmp[t] = own;
    __syncthreads();
    for (int off = 1; off < 128; off <<= 1) {
        int x = (t >= off && t < 128) ? tmp[t - off] : 0;
        __syncthreads();
        if (t < 128) tmp[t] += x;
        __syncthreads();
    }
    int nodeCnt = min(128, N - node0);
    if (t < nodeCnt) start[node0 + t] = lo + (tmp[t] - own);
    if (t < 128) hist[t] = lo + (tmp[t] - own);   // scatter cursor
    if (b == NBUCK2 - 1 && t == 0) start[N] = E;
    __syncthreads();
    for (int e = lo + t; e < hi; e += 256) {
        unsigned u = inter[e];
        int slot = atomicAdd(&hist[u >> 16], 1);
        csr_src[slot] = (int)(u & 0xffffu);
    }
}

// ---- MFMA GEMM2 (R9-proven) ----
__global__ void gemm2_mfma_kernel(const unsigned short* __restrict__ agg1e,
                                  const unsigned short* __restrict__ W2T,
                                  unsigned short* __restrict__ feat2, int N) {
    int lane = threadIdx.x & 63;
    int rbase = blockIdx.x * 64 + (threadIdx.x >> 6) * 16;
    int arow = rbase + (lane & 15);
    int arowc = min(arow, N - 1);
    int kb0 = (lane >> 4) * 8;

    f32x4 acc[4];
#pragma unroll
    for (int t = 0; t < 4; ++t) acc[t] = (f32x4){0.f, 0.f, 0.f, 0.f};

#pragma unroll
    for (int ks = 0; ks < 4; ++ks) {
        int kb = ks * 32 + kb0;
        bf16x8 afrag = *(const bf16x8*)(agg1e + (size_t)arowc * 128 + kb);
#pragma unroll
        for (int t = 0; t < 4; ++t) {
            int n = t * 16 + (lane & 15);
            bf16x8 bfrag = *(const bf16x8*)(W2T + n * WPAD + kb);
            acc[t] = __builtin_amdgcn_mfma_f32_16x16x32_bf16(afrag, bfrag, acc[t], 0, 0, 0);
        }
    }
    int orow0 = rbase + (lane >> 4) * 4;
    int col = lane & 15;
#pragma unroll
    for (int t = 0; t < 4; ++t)
#pragma unroll
        for (int r = 0; r < 4; ++r) {
            int row = orow0 + r;
            if (row < N)
                feat2[(size_t)row * 64 + t * 16 + col] = f32_to_bf16_raw(acc[t][r]);
        }
}

// ======= layer 1 fused GAT (R20: depth-2 software pipeline) =======
// Wave = 1 dst; 4 groups x 16 lanes (one coalesced 256B row per group
// VMEM op). Depth-2 rotation keeps 4 gather loads in flight per lane
// (R18's depth-1 had 2) -> doubles miss-level parallelism on the L2-miss
// path that the counters show is gat1's equilibrium.
#define GAT1_PROC(U0, U1)                                                     \
    {                                                                         \
        f32x2 f0[4], f1[4];                                                   \
        unpack8v(U0, f0); unpack8v(U1, f1);                                   \
        f32x2 p0 = fd2[0] * f0[0];                                            \
        f32x2 p1 = fd2[0] * f1[0];                                            \
        _Pragma("unroll")                                                     \
        for (int k = 1; k < 4; ++k) { p0 += fd2[k] * f0[k]; p1 += fd2[k] * f1[k]; } \
        float q0 = p0.x + p0.y, q1 = p1.x + p1.y;                             \
        q0 += __shfl_xor(q0, 1); q1 += __shfl_xor(q1, 1);                     \
        float w0 = EXP2(q0), w1 = EXP2(q1);                                   \
        f32x2 W0 = (f32x2){w0, w0}, W1 = (f32x2){w1, w1};                     \
        _Pragma("unroll")                                                     \
        for (int k = 0; k < 4; ++k) { acc2[k] += W0 * f0[k]; acc2[k] += W1 * f1[k]; } \
        l += w0 + w1;                                                         \
    }

__global__ void gat1_kernel(const unsigned short* __restrict__ feat1,
                            const int* __restrict__ csr_src,
                            const int* __restrict__ start,
                            unsigned short* __restrict__ agg1e, int N) {
    int wave = blockIdx.x * 4 + (threadIdx.x >> 6);
    if (wave >= N) return;
    int lane = threadIdx.x & 63;
    int grp = lane >> 4, gl = lane & 15;
    const char* fb = (const char*)feat1;       // uniform base; row = 256 B
    unsigned loff = (unsigned)gl << 4;
    f32x2 fd2[4];
    unpack8v(*(const uint4*)(fb + (((unsigned)wave << 8) + loff)), fd2);
    const float SC = 0.25f * LOG2E;            // fold score scale + log2e
    const f32x2 SC2 = (f32x2){SC, SC};
#pragma unroll
    for (int k = 0; k < 4; ++k) fd2[k] *= SC2;

    float l = 0.f;
    f32x2 acc2[4];
#pragma unroll
    for (int k = 0; k < 4; ++k) acc2[k] = (f32x2){0.f, 0.f};

    int e0 = start[wave], e1 = start[wave + 1];
    int nfull = (e1 - e0) >> 3;                // full 8-edge iterations
    int base = e0;
    uint4 a0, a1, b0, b1;
    if (nfull > 0) {
        int s0 = csr_src[base + grp];
        int s1 = csr_src[base + 4 + grp];
        a0 = *(const uint4*)(fb + (((unsigned)s0 << 8) + loff));
        a1 = *(const uint4*)(fb + (((unsigned)s1 << 8) + loff));
    }
    if (nfull > 1) {
        int s0 = csr_src[base + 8 + grp];
        int s1 = csr_src[base + 12 + grp];
        b0 = *(const uint4*)(fb + (((unsigned)s0 << 8) + loff));
        b1 = *(const uint4*)(fb + (((unsigned)s1 << 8) + loff));
    }
    for (int it = 0; it + 2 < nfull; ++it) {   // prefetch depth 2
        int nb = base + 16;
        int s0 = csr_src[nb + grp];
        int s1 = csr_src[nb + 4 + grp];
        uint4 n0 = *(const uint4*)(fb + (((unsigned)s0 << 8) + loff));
        uint4 n1 = *(const uint4*)(fb + (((unsigned)s1 << 8) + loff));
        GAT1_PROC(a0, a1);
        a0 = b0; a1 = b1; b0 = n0; b1 = n1;
        base += 8;
    }
    if (nfull > 1) { GAT1_PROC(a0, a1); a0 = b0; a1 = b1; base += 8; }
    if (nfull > 0) { GAT1_PROC(a0, a1); base += 8; }
    for (; base < e1; base += 4) {             // masked tail, 4 edges/step
        int ed = base + grp;
        bool act = ed < e1;
        int s = act ? csr_src[ed] : 0;
        uint4 u = *(const uint4*)(fb + (((unsigned)s << 8) + loff));
        f32x2 fv[4]; unpack8v(u, fv);
        f32x2 p = fd2[0] * fv[0];
#pragma unroll
        for (int k = 1; k < 4; ++k) p += fd2[k] * fv[k];
        float q = p.x + p.y;
        q += __shfl_xor(q, 1);
        float w = act ? EXP2(q) : 0.f;
        f32x2 W = (f32x2){w, w};
#pragma unroll
        for (int k = 0; k < 4; ++k) acc2[k] += W * fv[k];
        l += w;
    }
    // cross-group merge (pure sums)
#pragma unroll
    for (int off = 16; off <= 32; off <<= 1) {
        l += __shfl_xor(l, off);
#pragma unroll
        for (int k = 0; k < 4; ++k) {
            acc2[k].x += __shfl_xor(acc2[k].x, off);
            acc2[k].y += __shfl_xor(acc2[k].y, off);
        }
    }
    if (grp == 0) {
        float rcp = 1.f / fmaxf(l, 1e-9f);
        float v[8];
#pragma unroll
        for (int k = 0; k < 4; ++k) {
            float x0 = acc2[k].x * rcp;
            float x1 = acc2[k].y * rcp;
            v[2 * k]     = (x0 > 0.f) ? x0 : expm1f(x0);   // ELU fused
            v[2 * k + 1] = (x1 > 0.f) ? x1 : expm1f(x1);
        }
        uint4 pk;
        pk.x = (unsigned)f32_to_bf16_raw(v[0]) | ((unsigned)f32_to_bf16_raw(v[1]) << 16);
        pk.y = (unsigned)f32_to_bf16_raw(v[2]) | ((unsigned)f32_to_bf16_raw(v[3]) << 16);
        pk.z = (unsigned)f32_to_bf16_raw(v[4]) | ((unsigned)f32_to_bf16_raw(v[5]) << 16);
        pk.w = (unsigned)f32_to_bf16_raw(v[6]) | ((unsigned)f32_to_bf16_raw(v[7]) << 16);
        *(uint4*)(agg1e + (size_t)wave * 128 + gl * 8) = pk;
    }
}

// ======= layer 2 fused GAT (R20: depth-2 software pipeline) =======
#define GAT2_PROC(U0, U1)                                                     \
    {                                                                         \
        f32x2 f0[4], f1[4];                                                   \
        unpack8v(U0, f0); unpack8v(U1, f1);                                   \
        f32x2 p0 = fd2[0] * f0[0];                                            \
        f32x2 p1 = fd2[0] * f1[0];                                            \
        _Pragma("unroll")                                                     \
        for (int k = 1; k < 4; ++k) { p0 += fd2[k] * f0[k]; p1 += fd2[k] * f1[k]; } \
        float q0 = p0.x + p0.y, q1 = p1.x + p1.y;                             \
        q0 += __shfl_xor(q0, 1); q1 += __shfl_xor(q1, 1);                     \
        q0 += __shfl_xor(q0, 2); q1 += __shfl_xor(q1, 2);                     \
        q0 += __shfl_xor(q0, 4); q1 += __shfl_xor(q1, 4);                     \
        float w0 = EXP2(q0), w1 = EXP2(q1);                                   \
        f32x2 W0 = (f32x2){w0, w0}, W1 = (f32x2){w1, w1};                     \
        _Pragma("unroll")                                                     \
        for (int k = 0; k < 4; ++k) { acc2[k] += W0 * f0[k]; acc2[k] += W1 * f1[k]; } \
        l += w0 + w1;                                                         \
    }

__global__ void gat2_kernel(const unsigned short* __restrict__ feat2,
                            const int* __restrict__ csr_src,
                            const int* __restrict__ start,
                            void* __restrict__ out, int N,
                            const int* __restrict__ flag) {
    int wave = blockIdx.x * 4 + (threadIdx.x >> 6);
    if (wave >= N) return;
    int lane = threadIdx.x & 63;
    int grp = lane >> 3, gl = lane & 7;
    const int f = *flag;
    const char* fb = (const char*)feat2;       // uniform base; row = 128 B
    unsigned loff = (unsigned)gl << 4;
    f32x2 fd2[4];
    unpack8v(*(const uint4*)(fb + (((unsigned)wave << 7) + loff)), fd2);
    const float SC = 0.125f * LOG2E;
    const f32x2 SC2 = (f32x2){SC, SC};
#pragma unroll
    for (int k = 0; k < 4; ++k) fd2[k] *= SC2;

    float l = 0.f;
    f32x2 acc2[4];
#pragma unroll
    for (int k = 0; k < 4; ++k) acc2[k] = (f32x2){0.f, 0.f};

    int e0 = start[wave], e1 = start[wave + 1];
    int nfull = (e1 - e0) >> 4;                // full 16-edge iterations
    int base = e0;
    uint4 a0, a1, b0, b1;
    if (nfull > 0) {
        int s0 = csr_src[base + grp];
        int s1 = csr_src[base + 8 + grp];
        a0 = *(const uint4*)(fb + (((unsigned)s0 << 7) + loff));
        a1 = *(const uint4*)(fb + (((unsigned)s1 << 7) + loff));
    }
    if (nfull > 1) {
        int s0 = csr_src[base + 16 + grp];
        int s1 = csr_src[base + 24 + grp];
        b0 = *(const uint4*)(fb + (((unsigned)s0 << 7) + loff));
        b1 = *(const uint4*)(fb + (((unsigned)s1 << 7) + loff));
    }
    for (int it = 0; it + 2 < nfull; ++it) {   // prefetch depth 2
        int nb = base + 32;
        int s0 = csr_src[nb + grp];
        int s1 = csr_src[nb + 8 + grp];
        uint4 n0 = *(const uint4*)(fb + (((unsigned)s0 << 7) + loff));
        uint4 n1 = *(const uint4*)(fb + (((unsigned)s1 << 7) + loff));
        GAT2_PROC(a0, a1);
        a0 = b0; a1 = b1; b0 = n0; b1 = n1;
        base += 16;
    }
    if (nfull > 1) { GAT2_PROC(a0, a1); a0 = b0; a1 = b1; base += 16; }
    if (nfull > 0) { GAT2_PROC(a0, a1); base += 16; }
    for (; base < e1; base += 8) {
        int ed = base + grp;
        bool act = ed < e1;
        int s = act ? csr_src[ed] : 0;
        uint4 u = *(const uint4*)(fb + (((unsigned)s << 7) + loff));
        f32x2 fv[4]; unpack8v(u, fv);
        f32x2 p = fd2[0] * fv[0];
#pragma unroll
        for (int k = 1; k < 4; ++k) p += fd2[k] * fv[k];
        float q = p.x + p.y;
        q += __shfl_xor(q, 1);
        q += __shfl_xor(q, 2);
        q += __shfl_xor(q, 4);
        float w = act ? EXP2(q) : 0.f;
        f32x2 W = (f32x2){w, w};
#pragma unroll
        for (int k = 0; k < 4; ++k) acc2[k] += W * fv[k];
        l += w;
    }
#pragma unroll
    for (int off = 8; off <= 32; off <<= 1) {
        l += __shfl_xor(l, off);
#pragma unroll
        for (int k = 0; k < 4; ++k) {
            acc2[k].x += __shfl_xor(acc2[k].x, off);
            acc2[k].y += __shfl_xor(acc2[k].y, off);
        }
    }
    if (grp == 0) {
        float rcp = 1.f / fmaxf(l, 1e-9f);
        float v[8];
#pragma unroll
        for (int k = 0; k < 4; ++k) {
            v[2 * k]     = acc2[k].x * rcp;
            v[2 * k + 1] = acc2[k].y * rcp;
        }
        if (f) {
            float* op = (float*)out + (size_t)wave * 64 + gl * 8;
            *(float4*)(op)     = (float4){v[0], v[1], v[2], v[3]};
            *(float4*)(op + 4) = (float4){v[4], v[5], v[6], v[7]};
        } else {
            uint4 pk;
            pk.x = (unsigned)f32_to_bf16_raw(v[0]) | ((unsigned)f32_to_bf16_raw(v[1]) << 16);
            pk.y = (unsigned)f32_to_bf16_raw(v[2]) | ((unsigned)f32_to_bf16_raw(v[3]) << 16);
            pk.z = (unsigned)f32_to_bf16_raw(v[4]) | ((unsigned)f32_to_bf16_raw(v[5]) << 16);
            pk.w = (unsigned)f32_to_bf16_raw(v[6]) | ((unsigned)f32_to_bf16_raw(v[7]) << 16);
            *(uint4*)((unsigned short*)out + (size_t)wave * 64 + gl * 8) = pk;
        }
    }
}

extern "C" void kernel_launch(void* const* d_in, const int* in_sizes, int n_in,
                              void* d_out, int out_size, void* d_ws, size_t ws_size,
                              hipStream_t stream) {
    const void* h  = d_in[0];
    const void* W1 = d_in[1];
    const void* W2 = d_in[2];
    const int* src = (const int*)d_in[3];
    const int* dst = (const int*)d_in[4];

    float* ws = (float*)d_ws;
    // Layout (4-byte words), peak ~45.5 MB.
    unsigned short* feat1 = (unsigned short*)ws;
    unsigned short* agg1e = (unsigned short*)(ws + 3200000);
    unsigned short* feat2 = (unsigned short*)ws;      // after feat1 dead
    unsigned* inter       = (unsigned*)(ws + 6400000);
    int*   csr_src        = (int*)(ws + 9600000);
    int*   start          = (int*)(ws + 11200000);
    int*   flag           = (int*)(ws + 11330000);
    int*   bcnt           = (int*)(ws + 11331000);    // 391 ints
    int*   bcur           = bcnt + NBUCK2;            // 391 ints (contiguous)
    unsigned short* W1T   = (unsigned short*)(ws + 11340000);
    unsigned short* W2T   = (unsigned short*)(ws + 11350000);

    // zero bucket counters + cursors in one async memset (graph-safe)
    hipMemsetAsync(bcnt, 0, 2 * NBUCK2 * sizeof(int), stream);

    // K1: histogram | weight prep | dtype flag  (404 blocks)
    k1_count_prep_kernel<<<NB_A + 13, 256, 0, stream>>>(
        dst, N_EDGES, bcnt, W1, W2, W1T, W2T, flag);

    // K2: binA scatter-to-buckets | gemm1 rows [0, 25024)   (782 blocks)
    k2_binA_gemm1lo_kernel<<<NB_A + G1LO, 256, 0, stream>>>(
        src, dst, bcnt, bcur, inter, N_EDGES, h, W1T, feat1, N_NODES, flag);

    // K3: binB bucket->CSR | gemm1 rows [25024, 50000)      (782 blocks)
    k3_binB_gemm1hi_kernel<<<NBUCK2 + G1LO, 256, 0, stream>>>(
        inter, bcnt, csr_src, start, N_NODES, N_EDGES, h, W1T, feat1, flag);

    gat1_kernel<<<(N_NODES + 3) / 4, 256, 0, stream>>>(feat1, csr_src, start, agg1e, N_NODES);
    gemm2_mfma_kernel<<<(N_NODES + 63) / 64, 256, 0, stream>>>(agg1e, W2T, feat2, N_NODES);
    gat2_kernel<<<(N_NODES + 3) / 4, 256, 0, stream>>>(feat2, csr_src, start, d_out, N_NODES, flag);
}